// Round 1
// baseline (3910.228 us; speedup 1.0000x reference)
//
#include <hip/hip_runtime.h>
#include <math.h>

#define HEADS 12
#define DH    64
#define Dm    768
#define I3    2304
#define Bb    4
#define Nn    1024
#define Mm    4096
#define BHt   48

// minmax pair indices
#define P_X  0
#define P_W1 1
#define P_Q  2
#define P_K  3
#define P_V  4
#define P_A  5
#define P_O  6
#define P_W2 7

// ---------- helpers ----------
__device__ inline unsigned encf(float f) {
    unsigned u = __float_as_uint(f);
    return (u & 0x80000000u) ? ~u : (u | 0x80000000u);
}
__device__ inline float decf(unsigned u) {
    return (u & 0x80000000u) ? __uint_as_float(u & 0x7fffffffu) : __uint_as_float(~u);
}
// s = (max-min)/15 ; z = rint(15 - max/s)   (all f32, matching jnp)
__device__ inline void get_sz(const unsigned* scal, int pair, float* s, float* z) {
    float mn = decf(scal[2 * pair]);
    float mx = decf(scal[2 * pair + 1]);
    float ss = (mx - mn) / 15.0f;
    *s = ss;
    *z = rintf(15.0f - mx / ss);
}

__device__ inline void unpack16(int4 w, float* o) {
    o[0]  = (float)(signed char)(w.x);       o[1]  = (float)(signed char)(w.x >> 8);
    o[2]  = (float)(signed char)(w.x >> 16); o[3]  = (float)(signed char)(w.x >> 24);
    o[4]  = (float)(signed char)(w.y);       o[5]  = (float)(signed char)(w.y >> 8);
    o[6]  = (float)(signed char)(w.y >> 16); o[7]  = (float)(signed char)(w.y >> 24);
    o[8]  = (float)(signed char)(w.z);       o[9]  = (float)(signed char)(w.z >> 8);
    o[10] = (float)(signed char)(w.z >> 16); o[11] = (float)(signed char)(w.z >> 24);
    o[12] = (float)(signed char)(w.w);       o[13] = (float)(signed char)(w.w >> 8);
    o[14] = (float)(signed char)(w.w >> 16); o[15] = (float)(signed char)(w.w >> 24);
}

// 64-long int8 dot against a register-held float[64] (exact: products<=256, sums<=16384)
__device__ inline float qk_dot(const float* qf, const signed char* krow) {
    const int4* k4 = (const int4*)krow;
    float acc = 0.f;
#pragma unroll
    for (int c = 0; c < 4; ++c) {
        float kf[16];
        unpack16(k4[c], kf);
#pragma unroll
        for (int t = 0; t < 16; ++t) acc += qf[c * 16 + t] * kf[t];
    }
    return acc;
}

// ---------- kernels ----------
__global__ void k_init(unsigned* scal) {
    int t = threadIdx.x;
    if (t < 8) { scal[2 * t] = 0xFFFFFFFFu; scal[2 * t + 1] = 0u; }
}

__global__ __launch_bounds__(256) void k_minmax(const float* src, int rows, int cols, int ld,
                                                unsigned* scal, int pair) {
    __shared__ float rmn[256], rmx[256];
    int tid = threadIdx.x;
    long total = (long)rows * cols;
    long stride = (long)gridDim.x * blockDim.x;
    float mn = INFINITY, mx = -INFINITY;
    for (long idx = (long)blockIdx.x * blockDim.x + tid; idx < total; idx += stride) {
        float v;
        if (ld == cols) v = src[idx];
        else { long r = idx / cols; long c = idx - r * cols; v = src[r * ld + c]; }
        mn = fminf(mn, v); mx = fmaxf(mx, v);
    }
    rmn[tid] = mn; rmx[tid] = mx; __syncthreads();
    for (int s = 128; s > 0; s >>= 1) {
        if (tid < s) { rmn[tid] = fminf(rmn[tid], rmn[tid + s]); rmx[tid] = fmaxf(rmx[tid], rmx[tid + s]); }
        __syncthreads();
    }
    if (tid == 0) {
        atomicMin(&scal[2 * pair], encf(rmn[0]));
        atomicMax(&scal[2 * pair + 1], encf(rmx[0]));
    }
}

// quantize each row of src [rows x cols] (ld==cols for all users) -> int8 + integer row sums
__global__ __launch_bounds__(256) void k_quant_rows(const float* src, int cols, int ld,
                                                    const unsigned* scal, int pair,
                                                    signed char* dq, float* rowsum) {
    __shared__ float red[256];
    int r = blockIdx.x, tid = threadIdx.x;
    float s, z; get_sz(scal, pair, &s, &z);
    const float* row = src + (long)r * ld;
    signed char* drow = dq + (long)r * cols;
    float acc = 0.f;
    for (int c = tid; c < cols; c += 256) {
        float q = rintf(row[c] / s + z);
        drow[c] = (signed char)(int)q;
        acc += q;
    }
    red[tid] = acc; __syncthreads();
    for (int s2 = 128; s2 > 0; s2 >>= 1) { if (tid < s2) red[tid] += red[tid + s2]; __syncthreads(); }
    if (tid == 0) rowsum[r] = red[0];
}

__global__ __launch_bounds__(256) void k_rowsum(const float* src, int cols, float* rowsum) {
    __shared__ float red[256];
    int r = blockIdx.x, tid = threadIdx.x;
    const float* row = src + (long)r * cols;
    float acc = 0.f;
    for (int c = tid; c < cols; c += 256) acc += row[c];
    red[tid] = acc; __syncthreads();
    for (int s = 128; s > 0; s >>= 1) { if (tid < s) red[tid] += red[tid + s]; __syncthreads(); }
    if (tid == 0) rowsum[r] = red[0];
}

// C[i,j] = (sum_k A[i,k]*B[j,k] - colsumB[j]*zA - rowsumA[i]*zB + zA*zB*corrK)*(sA*sB) (+bias[j])
// A[M,K] int8, B[Nc,K] int8 (B^T layout). Tiles 64x64, BK=64. All dims multiples of 64.
__global__ __launch_bounds__(256) void k_gemm(const signed char* A, const signed char* B,
                                              const float* colsumB, const float* rowsumA,
                                              const float* bias, float* C, int K, int ldC,
                                              const unsigned* scal, int pairA, int pairB,
                                              float corrK) {
    __shared__ __align__(16) float As[64][68];
    __shared__ __align__(16) float Bs[64][68];
    int tid = threadIdx.x;
    int tx = tid & 15, ty = tid >> 4;
    long tM = (long)blockIdx.y * 64, tN = (long)blockIdx.x * 64;
    float c[4][4] = {};
    for (int k0 = 0; k0 < K; k0 += 64) {
#pragma unroll
        for (int p = 0; p < 4; ++p) {
            int lin = p * 256 + tid;
            int m = lin >> 4, kk = (lin & 15) << 2;
            int wA = *(const int*)(A + (tM + m) * K + k0 + kk);
            As[kk + 0][m] = (float)(signed char)(wA);
            As[kk + 1][m] = (float)(signed char)(wA >> 8);
            As[kk + 2][m] = (float)(signed char)(wA >> 16);
            As[kk + 3][m] = (float)(signed char)(wA >> 24);
            int wB = *(const int*)(B + (tN + m) * K + k0 + kk);
            Bs[kk + 0][m] = (float)(signed char)(wB);
            Bs[kk + 1][m] = (float)(signed char)(wB >> 8);
            Bs[kk + 2][m] = (float)(signed char)(wB >> 16);
            Bs[kk + 3][m] = (float)(signed char)(wB >> 24);
        }
        __syncthreads();
#pragma unroll 16
        for (int kk = 0; kk < 64; ++kk) {
            float4 a = *(const float4*)&As[kk][ty << 2];
            float4 b = *(const float4*)&Bs[kk][tx << 2];
            c[0][0] += a.x * b.x; c[0][1] += a.x * b.y; c[0][2] += a.x * b.z; c[0][3] += a.x * b.w;
            c[1][0] += a.y * b.x; c[1][1] += a.y * b.y; c[1][2] += a.y * b.z; c[1][3] += a.y * b.w;
            c[2][0] += a.z * b.x; c[2][1] += a.z * b.y; c[2][2] += a.z * b.z; c[2][3] += a.z * b.w;
            c[3][0] += a.w * b.x; c[3][1] += a.w * b.y; c[3][2] += a.w * b.z; c[3][3] += a.w * b.w;
        }
        __syncthreads();
    }
    float sA, zA, sB, zB;
    get_sz(scal, pairA, &sA, &zA);
    get_sz(scal, pairB, &sB, &zB);
    float sAB = sA * sB;
    float zz = (zA * zB) * corrK;
#pragma unroll
    for (int i = 0; i < 4; ++i)
#pragma unroll
        for (int j = 0; j < 4; ++j) {
            long row = tM + (ty << 2) + i;
            long col = tN + (tx << 2) + j;
            float v = (c[i][j] - colsumB[col] * zA - rowsumA[row] * zB + zz) * sAB;
            if (bias) v += bias[col];
            C[row * ldC + col] = v;
        }
}

// quantize q/k/v into heads layout [(bh*1024+i)*64+d]; row sums over d for qq and kq
__global__ __launch_bounds__(64) void k_quant_qkv(const float* xqkv, const unsigned* scal,
                                                  signed char* qq, signed char* kq, signed char* vq,
                                                  float* rowsum_qq, float* colsum_kq) {
    int blk = blockIdx.x;
    int bh = blk >> 10, i = blk & 1023;
    int d = threadIdx.x;
    int b = bh / HEADS, h = bh - HEADS * b;
    const float* row = xqkv + ((long)b * Nn + i) * I3 + h * DH;
    float sq, zq, sk, zk, sv, zv;
    get_sz(scal, P_Q, &sq, &zq);
    get_sz(scal, P_K, &sk, &zk);
    get_sz(scal, P_V, &sv, &zv);
    float q = rintf(row[d] / sq + zq);
    float k = rintf(row[768 + d] / sk + zk);
    float v = rintf(row[1536 + d] / sv + zv);
    long o = (long)blk * 64 + d;
    qq[o] = (signed char)(int)q;
    kq[o] = (signed char)(int)k;
    vq[o] = (signed char)(int)v;
    float s1 = q, s2 = k;
    for (int off = 32; off > 0; off >>= 1) {
        s1 += __shfl_down(s1, off);
        s2 += __shfl_down(s2, off);
    }
    if (d == 0) { rowsum_qq[blk] = s1; colsum_kq[blk] = s2; }
}

__global__ __launch_bounds__(256) void k_colsum_vq(const signed char* vq, float* colsum) {
    __shared__ float red[256];
    int bh = blockIdx.x >> 6, d = blockIdx.x & 63;
    int tid = threadIdx.x;
    float acc = 0.f;
    for (int j = tid; j < Nn; j += 256) acc += (float)vq[((long)bh * Nn + j) * 64 + d];
    red[tid] = acc; __syncthreads();
    for (int s = 128; s > 0; s >>= 1) { if (tid < s) red[tid] += red[tid + s]; __syncthreads(); }
    if (tid == 0) colsum[blockIdx.x] = red[0];
}

// Pass A: dots row -> rowmax, sumexp, global a-minmax (amax=1/sumexp, amin=exp(dmin-m)/sumexp)
__global__ __launch_bounds__(256) void k_attn_a(const signed char* qq, const signed char* kq,
                                                const float* rowsum_qq, const float* colsum_kq,
                                                unsigned* scal, float* rowmax, float* sumexp) {
    __shared__ float dots[1024];
    __shared__ float red[256];
    int blk = blockIdx.x;
    int bh = blk >> 10;
    int tid = threadIdx.x;
    float qf[64];
    {
        const int4* q4 = (const int4*)(qq + (long)blk * 64);
#pragma unroll
        for (int c = 0; c < 4; ++c) unpack16(q4[c], qf + c * 16);
    }
    float sq, zq, sk, zk;
    get_sz(scal, P_Q, &sq, &zq);
    get_sz(scal, P_K, &sk, &zk);
    float csc = (0.125f * sq) * sk;
    float rsq = rowsum_qq[blk];
    float lmax = -INFINITY, lmin = INFINITY;
    for (int j = tid; j < Nn; j += 256) {
        float acc = qk_dot(qf, kq + ((long)(bh << 10) + j) * 64);
        float dv = (acc - colsum_kq[(bh << 10) + j] * zq - rsq * zk) * csc;
        dots[j] = dv;
        lmax = fmaxf(lmax, dv); lmin = fminf(lmin, dv);
    }
    red[tid] = lmax; __syncthreads();
    for (int s = 128; s > 0; s >>= 1) { if (tid < s) red[tid] = fmaxf(red[tid], red[tid + s]); __syncthreads(); }
    float m = red[0]; __syncthreads();
    red[tid] = lmin; __syncthreads();
    for (int s = 128; s > 0; s >>= 1) { if (tid < s) red[tid] = fminf(red[tid], red[tid + s]); __syncthreads(); }
    float dmin = red[0]; __syncthreads();
    float ls = 0.f;
    for (int j = tid; j < Nn; j += 256) ls += expf(dots[j] - m);
    red[tid] = ls; __syncthreads();
    for (int s = 128; s > 0; s >>= 1) { if (tid < s) red[tid] += red[tid + s]; __syncthreads(); }
    if (tid == 0) {
        float se = red[0];
        rowmax[blk] = m;
        sumexp[blk] = se;
        float amax = 1.0f / se;               // value at argmax: expf(0)/se == 1.0f/se
        float amin = expf(dmin - m) / se;     // identical ops to elementwise path
        atomicMax(&scal[2 * P_A + 1], encf(amax));
        atomicMin(&scal[2 * P_A], encf(amin));
    }
}

// Pass B: recompute dots, quantize a, A*V with corrections -> out_mat [4096 x 768]
__global__ __launch_bounds__(256) void k_attn_b(const signed char* qq, const signed char* kq,
                                                const signed char* vq, const float* rowsum_qq,
                                                const float* colsum_kq, const float* colsum_vq,
                                                const float* rowmax, const float* sumexp,
                                                const unsigned* scal, float* out_mat) {
    __shared__ float aq[1024];
    __shared__ float red[256];
    __shared__ float s_rowsum;
    int blk = blockIdx.x;
    int bh = blk >> 10, i = blk & 1023;
    int tid = threadIdx.x;
    int b = bh / HEADS, h = bh - HEADS * b;
    float qf[64];
    {
        const int4* q4 = (const int4*)(qq + (long)blk * 64);
#pragma unroll
        for (int c = 0; c < 4; ++c) unpack16(q4[c], qf + c * 16);
    }
    float sq, zq, sk, zk, sv, zv, sa, za;
    get_sz(scal, P_Q, &sq, &zq);
    get_sz(scal, P_K, &sk, &zk);
    get_sz(scal, P_V, &sv, &zv);
    get_sz(scal, P_A, &sa, &za);
    float csc = (0.125f * sq) * sk;
    float rsq = rowsum_qq[blk];
    float m = rowmax[blk], se = sumexp[blk];
    float ls = 0.f;
    for (int j = tid; j < Nn; j += 256) {
        float acc = qk_dot(qf, kq + ((long)(bh << 10) + j) * 64);
        float dv = (acc - colsum_kq[(bh << 10) + j] * zq - rsq * zk) * csc;
        float av = expf(dv - m) / se;
        float aqv = rintf(av / sa + za);
        aq[j] = aqv;
        ls += aqv;
    }
    red[tid] = ls; __syncthreads();
    for (int s = 128; s > 0; s >>= 1) { if (tid < s) red[tid] += red[tid + s]; __syncthreads(); }
    if (tid == 0) s_rowsum = red[0];
    __syncthreads();
    int d = tid & 63, cch = tid >> 6;
    const signed char* vbase = vq + ((long)(bh << 10)) * 64;
    float acc = 0.f;
    for (int j = cch * 256; j < cch * 256 + 256; ++j)
        acc += aq[j] * (float)vbase[(long)j * 64 + d];
    red[tid] = acc; __syncthreads();
    if (cch == 0) {
        float sum = red[d] + red[64 + d] + red[128 + d] + red[192 + d];
        float outv = (sum - colsum_vq[bh * 64 + d] * za - s_rowsum * zv + (za * zv) * 1024.0f) * (sa * sv);
        out_mat[((long)b * Nn + i) * Dm + h * DH + d] = outv;
    }
}

// ---------- launch ----------
extern "C" void kernel_launch(void* const* d_in, const int* in_sizes, int n_in,
                              void* d_out, int out_size, void* d_ws, size_t ws_size,
                              hipStream_t stream) {
    const float* x     = (const float*)d_in[0];
    const float* w_qkv = (const float*)d_in[1];
    const float* w_out = (const float*)d_in[2];
    const float* b_out = (const float*)d_in[3];

    char* ws = (char*)d_ws;
    size_t off = 0;
    auto alloc = [&](size_t n) -> char* {
        char* p = ws + off;
        off = (off + n + 255) & ~(size_t)255;
        return p;
    };
    unsigned*    scal        = (unsigned*)alloc(64);
    float*       xqkv        = (float*)alloc((size_t)Mm * I3 * 4);
    float*       out_mat     = (float*)alloc((size_t)Mm * Dm * 4);
    signed char* xq          = (signed char*)alloc((size_t)Mm * Dm);
    signed char* wq          = (signed char*)alloc((size_t)I3 * Dm);
    signed char* w2q         = (signed char*)alloc((size_t)Dm * Dm);
    signed char* oq          = (signed char*)alloc((size_t)Mm * Dm);
    signed char* qq          = (signed char*)alloc((size_t)BHt * Nn * DH);
    signed char* kq          = (signed char*)alloc((size_t)BHt * Nn * DH);
    signed char* vq          = (signed char*)alloc((size_t)BHt * Nn * DH);
    float*       rowsum_xq   = (float*)alloc((size_t)Mm * 4);
    float*       colsum_w1   = (float*)alloc((size_t)I3 * 4);
    float*       colsum_w2   = (float*)alloc((size_t)Dm * 4);
    float*       rowsum_xqkv = (float*)alloc((size_t)Mm * 4);
    float*       rowsum_qq   = (float*)alloc((size_t)BHt * Nn * 4);
    float*       colsum_kq   = (float*)alloc((size_t)BHt * Nn * 4);
    float*       colsum_vq   = (float*)alloc((size_t)BHt * DH * 4);
    float*       rowmax      = (float*)alloc((size_t)BHt * Nn * 4);
    float*       sumexp      = (float*)alloc((size_t)BHt * Nn * 4);
    float*       oq_rowsum   = (float*)alloc((size_t)Mm * 4);

    k_init<<<1, 64, 0, stream>>>(scal);

    k_minmax<<<1024, 256, 0, stream>>>(x, Mm, Dm, Dm, scal, P_X);
    k_minmax<<<512, 256, 0, stream>>>(w_qkv, I3, Dm, Dm, scal, P_W1);
    k_minmax<<<256, 256, 0, stream>>>(w_out, Dm, Dm, Dm, scal, P_W2);

    k_quant_rows<<<Mm, 256, 0, stream>>>(x, Dm, Dm, scal, P_X, xq, rowsum_xq);
    k_quant_rows<<<I3, 256, 0, stream>>>(w_qkv, Dm, Dm, scal, P_W1, wq, colsum_w1);
    k_quant_rows<<<Dm, 256, 0, stream>>>(w_out, Dm, Dm, scal, P_W2, w2q, colsum_w2);

    {
        dim3 g(I3 / 64, Mm / 64);
        k_gemm<<<g, 256, 0, stream>>>(xq, wq, colsum_w1, rowsum_xq, nullptr, xqkv,
                                      Dm, I3, scal, P_X, P_W1, 768.0f);
    }
    k_rowsum<<<Mm, 256, 0, stream>>>(xqkv, I3, rowsum_xqkv);

    k_minmax<<<1024, 256, 0, stream>>>(xqkv, Mm, Dm, I3, scal, P_Q);
    k_minmax<<<1024, 256, 0, stream>>>(xqkv + 768, Mm, Dm, I3, scal, P_K);
    k_minmax<<<1024, 256, 0, stream>>>(xqkv + 1536, Mm, Dm, I3, scal, P_V);

    k_quant_qkv<<<BHt * Nn, 64, 0, stream>>>(xqkv, scal, qq, kq, vq, rowsum_qq, colsum_kq);
    k_colsum_vq<<<BHt * DH, 256, 0, stream>>>(vq, colsum_vq);

    k_attn_a<<<BHt * Nn, 256, 0, stream>>>(qq, kq, rowsum_qq, colsum_kq, scal, rowmax, sumexp);
    k_attn_b<<<BHt * Nn, 256, 0, stream>>>(qq, kq, vq, rowsum_qq, colsum_kq, colsum_vq,
                                           rowmax, sumexp, scal, out_mat);

    k_minmax<<<1024, 256, 0, stream>>>(out_mat, Mm, Dm, Dm, scal, P_O);
    k_quant_rows<<<Mm, 256, 0, stream>>>(out_mat, Dm, Dm, scal, P_O, oq, oq_rowsum);

    {
        dim3 g(Dm / 64, Mm / 64);
        k_gemm<<<g, 256, 0, stream>>>(oq, w2q, colsum_w2, rowsum_xqkv, b_out, (float*)d_out,
                                      Dm, Dm, scal, P_O, P_W2, 2304.0f);
    }
}

// Round 2
// 448.329 us; speedup vs baseline: 8.7218x; 8.7218x over previous
//
#include <hip/hip_runtime.h>
#include <math.h>

#define HEADS 12
#define DH    64
#define Dm    768
#define I3    2304
#define Nn    1024
#define Mm    4096
#define BHt   48

// minmax pair indices
#define P_X  0
#define P_W1 1
#define P_Q  2
#define P_K  3
#define P_V  4
#define P_A  5
#define P_O  6
#define P_W2 7

typedef int v4i __attribute__((ext_vector_type(4)));

// ---------- helpers ----------
__device__ inline unsigned encf(float f) {
    unsigned u = __float_as_uint(f);
    return (u & 0x80000000u) ? ~u : (u | 0x80000000u);
}
__device__ inline float decf(unsigned u) {
    return (u & 0x80000000u) ? __uint_as_float(u & 0x7fffffffu) : __uint_as_float(~u);
}
__device__ inline void get_sz(const unsigned* scal, int pair, float* s, float* z) {
    float mn = decf(scal[2 * pair]);
    float mx = decf(scal[2 * pair + 1]);
    float ss = (mx - mn) / 15.0f;
    *s = ss;
    *z = rintf(15.0f - mx / ss);
}

// ---------- kernels ----------
__global__ void k_init(unsigned* scal) {
    int t = threadIdx.x;
    if (t < 8) { scal[2 * t] = 0xFFFFFFFFu; scal[2 * t + 1] = 0u; }
}

// strided/flat minmax without any integer division: 256 blocks, each walks rows blockIdx.x,+256,...
__global__ __launch_bounds__(256) void k_minmax_rows(const float* src, int rows, int cols, int ld,
                                                     unsigned* scal, int pair) {
    __shared__ float rmn[256], rmx[256];
    int tid = threadIdx.x;
    float mn = INFINITY, mx = -INFINITY;
    for (int r = blockIdx.x; r < rows; r += 256) {
        const float* row = src + (long)r * ld;
        for (int c = tid; c < cols; c += 256) {
            float v = row[c];
            mn = fminf(mn, v); mx = fmaxf(mx, v);
        }
    }
    rmn[tid] = mn; rmx[tid] = mx; __syncthreads();
    for (int s = 128; s > 0; s >>= 1) {
        if (tid < s) { rmn[tid] = fminf(rmn[tid], rmn[tid + s]); rmx[tid] = fmaxf(rmx[tid], rmx[tid + s]); }
        __syncthreads();
    }
    if (tid == 0) {
        atomicMin(&scal[2 * pair], encf(rmn[0]));
        atomicMax(&scal[2 * pair + 1], encf(rmx[0]));
    }
}

// quantize each row -> int8 + integer row sums
__global__ __launch_bounds__(256) void k_quant_rows(const float* src, int cols, int ld,
                                                    const unsigned* scal, int pair,
                                                    signed char* dq, float* rowsum) {
    __shared__ float red[256];
    int r = blockIdx.x, tid = threadIdx.x;
    float s, z; get_sz(scal, pair, &s, &z);
    const float* row = src + (long)r * ld;
    signed char* drow = dq + (long)r * cols;
    float acc = 0.f;
    for (int c = tid; c < cols; c += 256) {
        float q = rintf(row[c] / s + z);
        drow[c] = (signed char)(int)q;
        acc += q;
    }
    red[tid] = acc; __syncthreads();
    for (int s2 = 128; s2 > 0; s2 >>= 1) { if (tid < s2) red[tid] += red[tid + s2]; __syncthreads(); }
    if (tid == 0) rowsum[r] = red[0];
}

__global__ __launch_bounds__(256) void k_rowsum(const float* src, int cols, float* rowsum) {
    __shared__ float red[256];
    int r = blockIdx.x, tid = threadIdx.x;
    const float* row = src + (long)r * cols;
    float acc = 0.f;
    for (int c = tid; c < cols; c += 256) acc += row[c];
    red[tid] = acc; __syncthreads();
    for (int s = 128; s > 0; s >>= 1) { if (tid < s) red[tid] += red[tid + s]; __syncthreads(); }
    if (tid == 0) rowsum[r] = red[0];
}

// MFMA int8 GEMM: C[i,j] = (sum_k A[i,k]*B[j,k] - colsumB[j]*zA - rowsumA[i]*zB + zA*zB*corrK)*(sA*sB) (+bias)
// A[M,K], B[N,K] int8 row-major (K-contiguous). Block tile 64x64 (4 waves of 32x32). K % 64 == 0.
__global__ __launch_bounds__(256) void k_gemm_mfma(const signed char* A, const signed char* B,
                                                   const float* colsumB, const float* rowsumA,
                                                   const float* bias, float* C, int K, int ldC,
                                                   const unsigned* scal, int pairA, int pairB,
                                                   float corrK) {
    int tid = threadIdx.x;
    int wave = tid >> 6, lane = tid & 63;
    int col16 = lane & 15, quad = lane >> 4;
    int wr = wave >> 1, wc = wave & 1;
    long rowbase = (long)blockIdx.y * 64 + wr * 32;
    long colbase = (long)blockIdx.x * 64 + wc * 32;
    v4i acc[2][2] = {};
    const signed char* aptr = A + (rowbase + col16) * K + quad * 16;
    const signed char* bptr = B + (colbase + col16) * K + quad * 16;
    for (int k0 = 0; k0 < K; k0 += 64) {
        v4i af0 = *(const v4i*)(aptr + k0);
        v4i af1 = *(const v4i*)(aptr + (long)16 * K + k0);
        v4i bf0 = *(const v4i*)(bptr + k0);
        v4i bf1 = *(const v4i*)(bptr + (long)16 * K + k0);
        acc[0][0] = __builtin_amdgcn_mfma_i32_16x16x64_i8(af0, bf0, acc[0][0], 0, 0, 0);
        acc[0][1] = __builtin_amdgcn_mfma_i32_16x16x64_i8(af0, bf1, acc[0][1], 0, 0, 0);
        acc[1][0] = __builtin_amdgcn_mfma_i32_16x16x64_i8(af1, bf0, acc[1][0], 0, 0, 0);
        acc[1][1] = __builtin_amdgcn_mfma_i32_16x16x64_i8(af1, bf1, acc[1][1], 0, 0, 0);
    }
    float sA, zA, sB, zB;
    get_sz(scal, pairA, &sA, &zA);
    get_sz(scal, pairB, &sB, &zB);
    float sAB = sA * sB;
    float zz = (zA * zB) * corrK;
#pragma unroll
    for (int i = 0; i < 2; ++i)
#pragma unroll
        for (int j = 0; j < 2; ++j) {
            long col = colbase + j * 16 + col16;
            float cs = colsumB[col] * zA;
            float bv = bias ? bias[col] : 0.f;
#pragma unroll
            for (int r = 0; r < 4; ++r) {
                long row = rowbase + i * 16 + quad * 4 + r;
                float v = ((float)acc[i][j][r] - cs - rowsumA[row] * zB + zz) * sAB + bv;
                C[row * ldC + col] = v;
            }
        }
}

// quantize q/k/v. qq,kq: [bh][i][d] (row-contig). vqT: [bh][d][i] (d-major). Row sums for qq, kq.
__global__ __launch_bounds__(64) void k_quant_qkv(const float* xqkv, const unsigned* scal,
                                                  signed char* qq, signed char* kq, signed char* vqT,
                                                  float* rowsum_qq, float* colsum_kq) {
    int blk = blockIdx.x;
    int bh = blk >> 10, i = blk & 1023;
    int d = threadIdx.x;
    int b = bh / HEADS, h = bh - HEADS * b;
    const float* row = xqkv + ((long)b * Nn + i) * I3 + h * DH;
    float sq, zq, sk, zk, sv, zv;
    get_sz(scal, P_Q, &sq, &zq);
    get_sz(scal, P_K, &sk, &zk);
    get_sz(scal, P_V, &sv, &zv);
    float q = rintf(row[d] / sq + zq);
    float k = rintf(row[768 + d] / sk + zk);
    float v = rintf(row[1536 + d] / sv + zv);
    long o = (long)blk * 64 + d;
    qq[o] = (signed char)(int)q;
    kq[o] = (signed char)(int)k;
    vqT[((long)bh * 64 + d) * 1024 + i] = (signed char)(int)v;
    float s1 = q, s2 = k;
    for (int off = 32; off > 0; off >>= 1) {
        s1 += __shfl_down(s1, off);
        s2 += __shfl_down(s2, off);
    }
    if (d == 0) { rowsum_qq[blk] = s1; colsum_kq[blk] = s2; }
}

// column sums of V (over keys j) from vqT rows — contiguous reads
__global__ __launch_bounds__(256) void k_colsum_vq(const signed char* vqT, float* colsum) {
    __shared__ float red[256];
    int tid = threadIdx.x;
    const signed char* row = vqT + (long)blockIdx.x * 1024;
    float acc = 0.f;
    for (int j = tid; j < Nn; j += 256) acc += (float)row[j];
    red[tid] = acc; __syncthreads();
    for (int s = 128; s > 0; s >>= 1) { if (tid < s) red[tid] += red[tid + s]; __syncthreads(); }
    if (tid == 0) colsum[blockIdx.x] = red[0];
}

// Pass A (MFMA): per block 64 Q-rows (4 waves x 16). Sweep1: row max/min of dots. Sweep2: sumexp.
__global__ __launch_bounds__(256) void k_attn_a2(const signed char* qq, const signed char* kq,
                                                 const float* rowsum_qq, const float* colsum_kq,
                                                 unsigned* scal, float* rowmax, float* sumexp) {
    __shared__ float redm[256];
    int blk = blockIdx.x;               // 48 bh * 16 itiles
    int bh = blk >> 4, itile = blk & 15;
    int tid = threadIdx.x;
    int wave = tid >> 6, lane = tid & 63;
    int col16 = lane & 15, quad = lane >> 4;
    int rowbase = itile * 64 + wave * 16;  // within bh
    const signed char* kbase = kq + (long)bh * Nn * 64;
    const float* csk_base = colsum_kq + bh * Nn;
    v4i afrag = *(const v4i*)(qq + ((long)bh * Nn + rowbase + col16) * 64 + quad * 16);
    float sq, zq, sk, zk;
    get_sz(scal, P_Q, &sq, &zq);
    get_sz(scal, P_K, &sk, &zk);
    float csc = (0.125f * sq) * sk;
    float rsq[4];
#pragma unroll
    for (int r = 0; r < 4; ++r) rsq[r] = rowsum_qq[bh * Nn + rowbase + quad * 4 + r];
    float lmax[4] = {-INFINITY, -INFINITY, -INFINITY, -INFINITY};
    float lmin[4] = {INFINITY, INFINITY, INFINITY, INFINITY};
    v4i zero = {0, 0, 0, 0};
    for (int jt = 0; jt < 64; ++jt) {
        v4i bfrag = *(const v4i*)(kbase + (long)(jt * 16 + col16) * 64 + quad * 16);
        v4i d = __builtin_amdgcn_mfma_i32_16x16x64_i8(afrag, bfrag, zero, 0, 0, 0);
        float csk = csk_base[jt * 16 + col16] * zq;
#pragma unroll
        for (int r = 0; r < 4; ++r) {
            float dv = ((float)d[r] - csk - rsq[r] * zk) * csc;
            lmax[r] = fmaxf(lmax[r], dv);
            lmin[r] = fminf(lmin[r], dv);
        }
    }
#pragma unroll
    for (int r = 0; r < 4; ++r) {
        for (int off = 1; off < 16; off <<= 1) {
            lmax[r] = fmaxf(lmax[r], __shfl_xor(lmax[r], off));
            lmin[r] = fminf(lmin[r], __shfl_xor(lmin[r], off));
        }
    }
    float se[4] = {0.f, 0.f, 0.f, 0.f};
    for (int jt = 0; jt < 64; ++jt) {
        v4i bfrag = *(const v4i*)(kbase + (long)(jt * 16 + col16) * 64 + quad * 16);
        v4i d = __builtin_amdgcn_mfma_i32_16x16x64_i8(afrag, bfrag, zero, 0, 0, 0);
        float csk = csk_base[jt * 16 + col16] * zq;
#pragma unroll
        for (int r = 0; r < 4; ++r) {
            float dv = ((float)d[r] - csk - rsq[r] * zk) * csc;
            se[r] += expf(dv - lmax[r]);
        }
    }
#pragma unroll
    for (int r = 0; r < 4; ++r)
        for (int off = 1; off < 16; off <<= 1) se[r] += __shfl_xor(se[r], off);
    float amax_c = -INFINITY, amin_c = INFINITY;
    if (col16 == 0) {
#pragma unroll
        for (int r = 0; r < 4; ++r) {
            int row = bh * Nn + rowbase + quad * 4 + r;
            rowmax[row] = lmax[r];
            sumexp[row] = se[r];
            amax_c = fmaxf(amax_c, 1.0f / se[r]);
            amin_c = fminf(amin_c, expf(lmin[r] - lmax[r]) / se[r]);
        }
    }
    redm[tid] = amax_c; __syncthreads();
    for (int s = 128; s > 0; s >>= 1) { if (tid < s) redm[tid] = fmaxf(redm[tid], redm[tid + s]); __syncthreads(); }
    if (tid == 0) atomicMax(&scal[2 * P_A + 1], encf(redm[0]));
    __syncthreads();
    redm[tid] = amin_c; __syncthreads();
    for (int s = 128; s > 0; s >>= 1) { if (tid < s) redm[tid] = fminf(redm[tid], redm[tid + s]); __syncthreads(); }
    if (tid == 0) atomicMin(&scal[2 * P_A], encf(redm[0]));
}

// Pass B (MFMA): recompute dots, quantize a (LDS C->A relayout per wave), PV via MFMA vs vqT.
__global__ __launch_bounds__(256) void k_attn_b2(const signed char* qq, const signed char* kq,
                                                 const signed char* vqT, const float* rowsum_qq,
                                                 const float* colsum_kq, const float* colsum_vq,
                                                 const float* rowmax, const float* sumexp,
                                                 const unsigned* scal, float* out_mat) {
    __shared__ __align__(16) signed char Aq[4][16 * 64];
    int blk = blockIdx.x;
    int bh = blk >> 4, itile = blk & 15;
    int tid = threadIdx.x;
    int wave = tid >> 6, lane = tid & 63;
    int col16 = lane & 15, quad = lane >> 4;
    int rowbase = itile * 64 + wave * 16;
    int b = bh / HEADS, h = bh - HEADS * b;
    const signed char* kbase = kq + (long)bh * Nn * 64;
    const signed char* vbase = vqT + (long)bh * 64 * 1024;
    const float* csk_base = colsum_kq + bh * Nn;
    v4i afrag = *(const v4i*)(qq + ((long)bh * Nn + rowbase + col16) * 64 + quad * 16);
    float sq, zq, sk, zk, sv, zv, sa, za;
    get_sz(scal, P_Q, &sq, &zq);
    get_sz(scal, P_K, &sk, &zk);
    get_sz(scal, P_V, &sv, &zv);
    get_sz(scal, P_A, &sa, &za);
    float csc = (0.125f * sq) * sk;
    float rsq[4], m[4], se[4];
#pragma unroll
    for (int r = 0; r < 4; ++r) {
        int row = bh * Nn + rowbase + quad * 4 + r;
        rsq[r] = rowsum_qq[row];
        m[r] = rowmax[row];
        se[r] = sumexp[row];
    }
    signed char* myAq = Aq[wave];
    v4i accPV[4] = {};
    float rs_a[4] = {0.f, 0.f, 0.f, 0.f};
    v4i zero = {0, 0, 0, 0};
    for (int ch = 0; ch < 16; ++ch) {
#pragma unroll
        for (int t = 0; t < 4; ++t) {
            int jt = ch * 4 + t;
            v4i bfrag = *(const v4i*)(kbase + (long)(jt * 16 + col16) * 64 + quad * 16);
            v4i d = __builtin_amdgcn_mfma_i32_16x16x64_i8(afrag, bfrag, zero, 0, 0, 0);
            float csk = csk_base[jt * 16 + col16] * zq;
#pragma unroll
            for (int r = 0; r < 4; ++r) {
                float dv = ((float)d[r] - csk - rsq[r] * zk) * csc;
                float av = expf(dv - m[r]) / se[r];
                float aqv = rintf(av / sa + za);
                rs_a[r] += aqv;
                myAq[(quad * 4 + r) * 64 + t * 16 + col16] = (signed char)(int)aqv;
            }
        }
        asm volatile("s_waitcnt lgkmcnt(0)" ::: "memory");
        v4i pa = *(const v4i*)(myAq + col16 * 64 + quad * 16);
#pragma unroll
        for (int g = 0; g < 4; ++g) {
            v4i bv = *(const v4i*)(vbase + ((long)(g * 16 + col16)) * 1024 + ch * 64 + quad * 16);
            accPV[g] = __builtin_amdgcn_mfma_i32_16x16x64_i8(pa, bv, accPV[g], 0, 0, 0);
        }
        asm volatile("s_waitcnt lgkmcnt(0)" ::: "memory");
    }
#pragma unroll
    for (int r = 0; r < 4; ++r)
        for (int off = 1; off < 16; off <<= 1) rs_a[r] += __shfl_xor(rs_a[r], off);
    float sav = sa * sv;
    float zz = (za * zv) * 1024.0f;
#pragma unroll
    for (int g = 0; g < 4; ++g) {
        int d = g * 16 + col16;
        float cs = colsum_vq[bh * 64 + d] * za;
#pragma unroll
        for (int r = 0; r < 4; ++r) {
            int i = rowbase + quad * 4 + r;
            float v = ((float)accPV[g][r] - cs - rs_a[r] * zv + zz) * sav;
            out_mat[((long)b * Nn + i) * Dm + h * DH + d] = v;
        }
    }
}

// ---------- launch ----------
extern "C" void kernel_launch(void* const* d_in, const int* in_sizes, int n_in,
                              void* d_out, int out_size, void* d_ws, size_t ws_size,
                              hipStream_t stream) {
    const float* x     = (const float*)d_in[0];
    const float* w_qkv = (const float*)d_in[1];
    const float* w_out = (const float*)d_in[2];
    const float* b_out = (const float*)d_in[3];

    char* ws = (char*)d_ws;
    size_t off = 0;
    auto alloc = [&](size_t n) -> char* {
        char* p = ws + off;
        off = (off + n + 255) & ~(size_t)255;
        return p;
    };
    unsigned*    scal        = (unsigned*)alloc(64);
    float*       xqkv        = (float*)alloc((size_t)Mm * I3 * 4);
    float*       out_mat     = (float*)alloc((size_t)Mm * Dm * 4);
    signed char* xq          = (signed char*)alloc((size_t)Mm * Dm);
    signed char* wq          = (signed char*)alloc((size_t)I3 * Dm);
    signed char* w2q         = (signed char*)alloc((size_t)Dm * Dm);
    signed char* oq          = (signed char*)alloc((size_t)Mm * Dm);
    signed char* qq          = (signed char*)alloc((size_t)BHt * Nn * DH);
    signed char* kq          = (signed char*)alloc((size_t)BHt * Nn * DH);
    signed char* vqT         = (signed char*)alloc((size_t)BHt * Nn * DH);
    float*       rowsum_xq   = (float*)alloc((size_t)Mm * 4);
    float*       colsum_w1   = (float*)alloc((size_t)I3 * 4);
    float*       colsum_w2   = (float*)alloc((size_t)Dm * 4);
    float*       rowsum_xqkv = (float*)alloc((size_t)Mm * 4);
    float*       rowsum_qq   = (float*)alloc((size_t)BHt * Nn * 4);
    float*       colsum_kq   = (float*)alloc((size_t)BHt * Nn * 4);
    float*       colsum_vq   = (float*)alloc((size_t)BHt * DH * 4);
    float*       rowmax      = (float*)alloc((size_t)BHt * Nn * 4);
    float*       sumexp      = (float*)alloc((size_t)BHt * Nn * 4);
    float*       oq_rowsum   = (float*)alloc((size_t)Mm * 4);

    k_init<<<1, 64, 0, stream>>>(scal);

    k_minmax_rows<<<256, 256, 0, stream>>>(x, Mm, Dm, Dm, scal, P_X);
    k_minmax_rows<<<256, 256, 0, stream>>>(w_qkv, I3, Dm, Dm, scal, P_W1);
    k_minmax_rows<<<256, 256, 0, stream>>>(w_out, Dm, Dm, Dm, scal, P_W2);

    k_quant_rows<<<Mm, 256, 0, stream>>>(x, Dm, Dm, scal, P_X, xq, rowsum_xq);
    k_quant_rows<<<I3, 256, 0, stream>>>(w_qkv, Dm, Dm, scal, P_W1, wq, colsum_w1);
    k_quant_rows<<<Dm, 256, 0, stream>>>(w_out, Dm, Dm, scal, P_W2, w2q, colsum_w2);

    {
        dim3 g(I3 / 64, Mm / 64);
        k_gemm_mfma<<<g, 256, 0, stream>>>(xq, wq, colsum_w1, rowsum_xq, nullptr, xqkv,
                                           Dm, I3, scal, P_X, P_W1, 768.0f);
    }
    k_rowsum<<<Mm, 256, 0, stream>>>(xqkv, I3, rowsum_xqkv);

    k_minmax_rows<<<256, 256, 0, stream>>>(xqkv, Mm, Dm, I3, scal, P_Q);
    k_minmax_rows<<<256, 256, 0, stream>>>(xqkv + 768, Mm, Dm, I3, scal, P_K);
    k_minmax_rows<<<256, 256, 0, stream>>>(xqkv + 1536, Mm, Dm, I3, scal, P_V);

    k_quant_qkv<<<BHt * Nn, 64, 0, stream>>>(xqkv, scal, qq, kq, vqT, rowsum_qq, colsum_kq);
    k_colsum_vq<<<BHt * DH, 256, 0, stream>>>(vqT, colsum_vq);

    k_attn_a2<<<BHt * 16, 256, 0, stream>>>(qq, kq, rowsum_qq, colsum_kq, scal, rowmax, sumexp);
    k_attn_b2<<<BHt * 16, 256, 0, stream>>>(qq, kq, vqT, rowsum_qq, colsum_kq, colsum_vq,
                                            rowmax, sumexp, scal, out_mat);

    k_minmax_rows<<<256, 256, 0, stream>>>(out_mat, Mm, Dm, Dm, scal, P_O);
    k_quant_rows<<<Mm, 256, 0, stream>>>(out_mat, Dm, Dm, scal, P_O, oq, oq_rowsum);

    {
        dim3 g(Dm / 64, Mm / 64);
        k_gemm_mfma<<<g, 256, 0, stream>>>(oq, w2q, colsum_w2, rowsum_xqkv, b_out, (float*)d_out,
                                           Dm, Dm, scal, P_O, P_W2, 2304.0f);
    }
}

// Round 3
// 336.394 us; speedup vs baseline: 11.6239x; 1.3327x over previous
//
#include <hip/hip_runtime.h>
#include <math.h>

#define HEADS 12
#define DH    64
#define Dm    768
#define I3    2304
#define Nn    1024
#define Mm    4096
#define BHt   48

// minmax pair indices
#define P_X  0
#define P_W1 1
#define P_Q  2
#define P_K  3
#define P_V  4
#define P_A  5
#define P_O  6
#define P_W2 7

typedef int v4i __attribute__((ext_vector_type(4)));

// ---------- helpers ----------
__device__ inline unsigned encf(float f) {
    unsigned u = __float_as_uint(f);
    return (u & 0x80000000u) ? ~u : (u | 0x80000000u);
}
__device__ inline float decf(unsigned u) {
    return (u & 0x80000000u) ? __uint_as_float(u & 0x7fffffffu) : __uint_as_float(~u);
}
__device__ inline void get_sz(const unsigned* scal, int pair, float* s, float* z) {
    float mn = decf(scal[2 * pair]);
    float mx = decf(scal[2 * pair + 1]);
    float ss = (mx - mn) / 15.0f;
    *s = ss;
    *z = rintf(15.0f - mx / ss);
}

// ---------- kernels ----------
// init scal + zero rowsum_xqkv (4096 floats)
__global__ __launch_bounds__(256) void k_init(unsigned* scal, float* zbuf, int nz) {
    int g = blockIdx.x * 256 + threadIdx.x;
    if (g < nz) zbuf[g] = 0.f;
    if (g < 8) { scal[2 * g] = 0xFFFFFFFFu; scal[2 * g + 1] = 0u; }
}

// fused minmax of x (4096x768), w_qkv (2304x768), w_out (768x768); all cols=768
__global__ __launch_bounds__(256) void k_minmax3(const float* x, const float* w1, const float* w2,
                                                 unsigned* scal) {
    __shared__ float rmn[256], rmx[256];
    int bid = blockIdx.x, tid = threadIdx.x;
    const float* src; int rows, pair, b0, nb;
    if (bid < 256)      { src = x;  rows = 4096; pair = P_X;  b0 = 0;   nb = 256; }
    else if (bid < 384) { src = w1; rows = 2304; pair = P_W1; b0 = 256; nb = 128; }
    else                { src = w2; rows = 768;  pair = P_W2; b0 = 384; nb = 64;  }
    float mn = INFINITY, mx = -INFINITY;
    for (int r = bid - b0; r < rows; r += nb) {
        const float* row = src + (long)r * 768;
#pragma unroll
        for (int k = 0; k < 3; ++k) {
            float v = row[tid + k * 256];
            mn = fminf(mn, v); mx = fmaxf(mx, v);
        }
    }
    rmn[tid] = mn; rmx[tid] = mx; __syncthreads();
    for (int s = 128; s > 0; s >>= 1) {
        if (tid < s) { rmn[tid] = fminf(rmn[tid], rmn[tid + s]); rmx[tid] = fmaxf(rmx[tid], rmx[tid + s]); }
        __syncthreads();
    }
    if (tid == 0) {
        atomicMin(&scal[2 * pair], encf(rmn[0]));
        atomicMax(&scal[2 * pair + 1], encf(rmx[0]));
    }
}

// fused quantization of x / w_qkv / w_out (cols=768) -> int8 + row sums
__global__ __launch_bounds__(256) void k_quant3(const float* x, const float* w1, const float* w2,
                                                const unsigned* scal,
                                                signed char* xq, signed char* wq, signed char* w2q,
                                                float* rs_x, float* rs_w1, float* rs_w2) {
    __shared__ float red[256];
    int bid = blockIdx.x, tid = threadIdx.x;
    const float* src; signed char* dq; float* rs; int pair, r;
    if (bid < 4096)      { src = x;  dq = xq;  rs = rs_x;  pair = P_X;  r = bid; }
    else if (bid < 6400) { src = w1; dq = wq;  rs = rs_w1; pair = P_W1; r = bid - 4096; }
    else                 { src = w2; dq = w2q; rs = rs_w2; pair = P_W2; r = bid - 6400; }
    float s, z; get_sz(scal, pair, &s, &z);
    const float* row = src + (long)r * 768;
    signed char* drow = dq + (long)r * 768;
    float acc = 0.f;
#pragma unroll
    for (int k = 0; k < 3; ++k) {
        int c = tid + k * 256;
        float q = rintf(row[c] / s + z);
        drow[c] = (signed char)(int)q;
        acc += q;
    }
    red[tid] = acc; __syncthreads();
    for (int s2 = 128; s2 > 0; s2 >>= 1) { if (tid < s2) red[tid] += red[tid + s2]; __syncthreads(); }
    if (tid == 0) rs[r] = red[0];
}

// single-array quant (for out_mat -> oq), cols=768
__global__ __launch_bounds__(256) void k_quant_rows(const float* src, const unsigned* scal, int pair,
                                                    signed char* dq, float* rowsum) {
    __shared__ float red[256];
    int r = blockIdx.x, tid = threadIdx.x;
    float s, z; get_sz(scal, pair, &s, &z);
    const float* row = src + (long)r * 768;
    signed char* drow = dq + (long)r * 768;
    float acc = 0.f;
#pragma unroll
    for (int k = 0; k < 3; ++k) {
        int c = tid + k * 256;
        float q = rintf(row[c] / s + z);
        drow[c] = (signed char)(int)q;
        acc += q;
    }
    red[tid] = acc; __syncthreads();
    for (int s2 = 128; s2 > 0; s2 >>= 1) { if (tid < s2) red[tid] += red[tid + s2]; __syncthreads(); }
    if (tid == 0) rowsum[r] = red[0];
}

// MFMA int8 GEMM, block tile 128x64 (4 waves x 32 rows, 64 cols).
// C[i,j] = (acc - colsumB[j]*zA - rowsumA[i]*zB + zA*zB*corrK)*(sA*sB) (+bias)
// do_stats: also atomicAdd per-row sums of C into rowsum_out and global minmax of C
// into scal_mm pair P_Q + colbase/768 (used for GEMM1 -> xqkv stats fusion).
__global__ __launch_bounds__(256) void k_gemm_mfma(const signed char* A, const signed char* B,
                                                   const float* colsumB, const float* rowsumA,
                                                   const float* bias, float* C, int K, int ldC,
                                                   const unsigned* scal, int pairA, int pairB,
                                                   float corrK, int do_stats, float* rowsum_out,
                                                   unsigned* scal_mm) {
    __shared__ float red[256];
    int tid = threadIdx.x;
    int wave = tid >> 6, lane = tid & 63;
    int col16 = lane & 15, quad = lane >> 4;
    long rowbase = (long)blockIdx.y * 128 + wave * 32;
    long colbase = (long)blockIdx.x * 64;
    v4i acc[2][4] = {};
    const signed char* aptr = A + (rowbase + col16) * K + quad * 16;
    const signed char* bptr = B + (colbase + col16) * K + quad * 16;
    for (int k0 = 0; k0 < K; k0 += 64) {
        v4i af0 = *(const v4i*)(aptr + k0);
        v4i af1 = *(const v4i*)(aptr + (long)16 * K + k0);
        v4i bf[4];
#pragma unroll
        for (int g = 0; g < 4; ++g) bf[g] = *(const v4i*)(bptr + (long)(g * 16) * K + k0);
#pragma unroll
        for (int g = 0; g < 4; ++g) {
            acc[0][g] = __builtin_amdgcn_mfma_i32_16x16x64_i8(af0, bf[g], acc[0][g], 0, 0, 0);
            acc[1][g] = __builtin_amdgcn_mfma_i32_16x16x64_i8(af1, bf[g], acc[1][g], 0, 0, 0);
        }
    }
    float sA, zA, sB, zB;
    get_sz(scal, pairA, &sA, &zA);
    get_sz(scal, pairB, &sB, &zB);
    float sAB = sA * sB;
    float zz = (zA * zB) * corrK;
    float vmn = INFINITY, vmx = -INFINITY;
    float rowpart[2][4] = {};
#pragma unroll
    for (int i2 = 0; i2 < 2; ++i2)
#pragma unroll
        for (int g = 0; g < 4; ++g) {
            long col = colbase + g * 16 + col16;
            float cs = colsumB[col] * zA;
            float bv = bias ? bias[col] : 0.f;
#pragma unroll
            for (int r = 0; r < 4; ++r) {
                long row = rowbase + i2 * 16 + quad * 4 + r;
                float v = ((float)acc[i2][g][r] - cs - rowsumA[row] * zB + zz) * sAB + bv;
                C[row * ldC + col] = v;
                rowpart[i2][r] += v;
                vmn = fminf(vmn, v); vmx = fmaxf(vmx, v);
            }
        }
    if (do_stats) {
        // per-row partial sums: reduce across the 16 col16 lanes of each quad-group
#pragma unroll
        for (int i2 = 0; i2 < 2; ++i2)
#pragma unroll
            for (int r = 0; r < 4; ++r) {
                float s = rowpart[i2][r];
                s += __shfl_xor(s, 1); s += __shfl_xor(s, 2);
                s += __shfl_xor(s, 4); s += __shfl_xor(s, 8);
                if (col16 == 0)
                    atomicAdd(&rowsum_out[rowbase + i2 * 16 + quad * 4 + r], s);
            }
        int pair = P_Q + (int)(colbase / 768);
        red[tid] = vmx; __syncthreads();
        for (int s = 128; s > 0; s >>= 1) { if (tid < s) red[tid] = fmaxf(red[tid], red[tid + s]); __syncthreads(); }
        if (tid == 0) atomicMax(&scal_mm[2 * pair + 1], encf(red[0]));
        __syncthreads();
        red[tid] = vmn; __syncthreads();
        for (int s = 128; s > 0; s >>= 1) { if (tid < s) red[tid] = fminf(red[tid], red[tid + s]); __syncthreads(); }
        if (tid == 0) atomicMin(&scal_mm[2 * pair], encf(red[0]));
    }
}

// quantize q/k/v. qq,kq: [bh][i][d] (row-contig). vqT: [bh][d][i] (d-major). Row sums for qq, kq.
__global__ __launch_bounds__(64) void k_quant_qkv(const float* xqkv, const unsigned* scal,
                                                  signed char* qq, signed char* kq, signed char* vqT,
                                                  float* rowsum_qq, float* colsum_kq) {
    int blk = blockIdx.x;
    int bh = blk >> 10, i = blk & 1023;
    int d = threadIdx.x;
    int b = bh / HEADS, h = bh - HEADS * b;
    const float* row = xqkv + ((long)b * Nn + i) * I3 + h * DH;
    float sq, zq, sk, zk, sv, zv;
    get_sz(scal, P_Q, &sq, &zq);
    get_sz(scal, P_K, &sk, &zk);
    get_sz(scal, P_V, &sv, &zv);
    float q = rintf(row[d] / sq + zq);
    float k = rintf(row[768 + d] / sk + zk);
    float v = rintf(row[1536 + d] / sv + zv);
    long o = (long)blk * 64 + d;
    qq[o] = (signed char)(int)q;
    kq[o] = (signed char)(int)k;
    vqT[((long)bh * 64 + d) * 1024 + i] = (signed char)(int)v;
    float s1 = q, s2 = k;
    for (int off = 32; off > 0; off >>= 1) {
        s1 += __shfl_down(s1, off);
        s2 += __shfl_down(s2, off);
    }
    if (d == 0) { rowsum_qq[blk] = s1; colsum_kq[blk] = s2; }
}

// column sums of V (over keys j) from vqT rows — contiguous reads
__global__ __launch_bounds__(256) void k_colsum_vq(const signed char* vqT, float* colsum) {
    __shared__ float red[256];
    int tid = threadIdx.x;
    const signed char* row = vqT + (long)blockIdx.x * 1024;
    float acc = 0.f;
    for (int j = tid; j < Nn; j += 256) acc += (float)row[j];
    red[tid] = acc; __syncthreads();
    for (int s = 128; s > 0; s >>= 1) { if (tid < s) red[tid] += red[tid + s]; __syncthreads(); }
    if (tid == 0) colsum[blockIdx.x] = red[0];
}

// Pass A (MFMA): per block 64 Q-rows (4 waves x 16). Sweep1: row max/min of dots. Sweep2: sumexp.
__global__ __launch_bounds__(256) void k_attn_a2(const signed char* qq, const signed char* kq,
                                                 const float* rowsum_qq, const float* colsum_kq,
                                                 unsigned* scal, float* rowmax, float* sumexp) {
    __shared__ float redm[256];
    int blk = blockIdx.x;               // 48 bh * 16 itiles
    int bh = blk >> 4, itile = blk & 15;
    int tid = threadIdx.x;
    int wave = tid >> 6, lane = tid & 63;
    int col16 = lane & 15, quad = lane >> 4;
    int rowbase = itile * 64 + wave * 16;  // within bh
    const signed char* kbase = kq + (long)bh * Nn * 64;
    const float* csk_base = colsum_kq + bh * Nn;
    v4i afrag = *(const v4i*)(qq + ((long)bh * Nn + rowbase + col16) * 64 + quad * 16);
    float sq, zq, sk, zk;
    get_sz(scal, P_Q, &sq, &zq);
    get_sz(scal, P_K, &sk, &zk);
    float csc = (0.125f * sq) * sk;
    float rsq[4];
#pragma unroll
    for (int r = 0; r < 4; ++r) rsq[r] = rowsum_qq[bh * Nn + rowbase + quad * 4 + r];
    float lmax[4] = {-INFINITY, -INFINITY, -INFINITY, -INFINITY};
    float lmin[4] = {INFINITY, INFINITY, INFINITY, INFINITY};
    v4i zero = {0, 0, 0, 0};
    for (int jt = 0; jt < 64; ++jt) {
        v4i bfrag = *(const v4i*)(kbase + (long)(jt * 16 + col16) * 64 + quad * 16);
        v4i d = __builtin_amdgcn_mfma_i32_16x16x64_i8(afrag, bfrag, zero, 0, 0, 0);
        float csk = csk_base[jt * 16 + col16] * zq;
#pragma unroll
        for (int r = 0; r < 4; ++r) {
            float dv = ((float)d[r] - csk - rsq[r] * zk) * csc;
            lmax[r] = fmaxf(lmax[r], dv);
            lmin[r] = fminf(lmin[r], dv);
        }
    }
#pragma unroll
    for (int r = 0; r < 4; ++r) {
        for (int off = 1; off < 16; off <<= 1) {
            lmax[r] = fmaxf(lmax[r], __shfl_xor(lmax[r], off));
            lmin[r] = fminf(lmin[r], __shfl_xor(lmin[r], off));
        }
    }
    float se[4] = {0.f, 0.f, 0.f, 0.f};
    for (int jt = 0; jt < 64; ++jt) {
        v4i bfrag = *(const v4i*)(kbase + (long)(jt * 16 + col16) * 64 + quad * 16);
        v4i d = __builtin_amdgcn_mfma_i32_16x16x64_i8(afrag, bfrag, zero, 0, 0, 0);
        float csk = csk_base[jt * 16 + col16] * zq;
#pragma unroll
        for (int r = 0; r < 4; ++r) {
            float dv = ((float)d[r] - csk - rsq[r] * zk) * csc;
            se[r] += expf(dv - lmax[r]);
        }
    }
#pragma unroll
    for (int r = 0; r < 4; ++r)
        for (int off = 1; off < 16; off <<= 1) se[r] += __shfl_xor(se[r], off);
    float amax_c = -INFINITY, amin_c = INFINITY;
    if (col16 == 0) {
#pragma unroll
        for (int r = 0; r < 4; ++r) {
            int row = bh * Nn + rowbase + quad * 4 + r;
            rowmax[row] = lmax[r];
            sumexp[row] = se[r];
            amax_c = fmaxf(amax_c, 1.0f / se[r]);
            amin_c = fminf(amin_c, expf(lmin[r] - lmax[r]) / se[r]);
        }
    }
    redm[tid] = amax_c; __syncthreads();
    for (int s = 128; s > 0; s >>= 1) { if (tid < s) redm[tid] = fmaxf(redm[tid], redm[tid + s]); __syncthreads(); }
    if (tid == 0) atomicMax(&scal[2 * P_A + 1], encf(redm[0]));
    __syncthreads();
    redm[tid] = amin_c; __syncthreads();
    for (int s = 128; s > 0; s >>= 1) { if (tid < s) redm[tid] = fminf(redm[tid], redm[tid + s]); __syncthreads(); }
    if (tid == 0) atomicMin(&scal[2 * P_A], encf(redm[0]));
}

// Pass B (MFMA): recompute dots, quantize a (fast path + exact-fallback guard, bit-identical
// to the exact chain), LDS C->A relayout per wave, PV via MFMA vs vqT. Fused P_O minmax.
__global__ __launch_bounds__(256) void k_attn_b2(const signed char* qq, const signed char* kq,
                                                 const signed char* vqT, const float* rowsum_qq,
                                                 const float* colsum_kq, const float* colsum_vq,
                                                 const float* rowmax, const float* sumexp,
                                                 unsigned* scal, float* out_mat) {
    __shared__ __align__(16) signed char Aq[4][16 * 64];
    __shared__ float red[256];
    int blk = blockIdx.x;
    int bh = blk >> 4, itile = blk & 15;
    int tid = threadIdx.x;
    int wave = tid >> 6, lane = tid & 63;
    int col16 = lane & 15, quad = lane >> 4;
    int rowbase = itile * 64 + wave * 16;
    int b = bh / HEADS, h = bh - HEADS * b;
    const signed char* kbase = kq + (long)bh * Nn * 64;
    const signed char* vbase = vqT + (long)bh * 64 * 1024;
    const float* csk_base = colsum_kq + bh * Nn;
    v4i afrag = *(const v4i*)(qq + ((long)bh * Nn + rowbase + col16) * 64 + quad * 16);
    float sq, zq, sk, zk, sv, zv, sa, za;
    get_sz(scal, P_Q, &sq, &zq);
    get_sz(scal, P_K, &sk, &zk);
    get_sz(scal, P_V, &sv, &zv);
    get_sz(scal, P_A, &sa, &za);
    float csc = (0.125f * sq) * sk;
    float rsq[4], m[4], se[4], crcp[4];
#pragma unroll
    for (int r = 0; r < 4; ++r) {
        int row = bh * Nn + rowbase + quad * 4 + r;
        rsq[r] = rowsum_qq[row];
        m[r] = rowmax[row];
        se[r] = sumexp[row];
        crcp[r] = 1.0f / (se[r] * sa);   // fast-path scale; guarded below
    }
    signed char* myAq = Aq[wave];
    v4i accPV[4] = {};
    float rs_a[4] = {0.f, 0.f, 0.f, 0.f};
    v4i zero = {0, 0, 0, 0};
    for (int ch = 0; ch < 16; ++ch) {
#pragma unroll
        for (int t = 0; t < 4; ++t) {
            int jt = ch * 4 + t;
            v4i bfrag = *(const v4i*)(kbase + (long)(jt * 16 + col16) * 64 + quad * 16);
            v4i d = __builtin_amdgcn_mfma_i32_16x16x64_i8(afrag, bfrag, zero, 0, 0, 0);
            float csk = csk_base[jt * 16 + col16] * zq;
#pragma unroll
            for (int r = 0; r < 4; ++r) {
                float dv = ((float)d[r] - csk - rsq[r] * zk) * csc;
                float es = dv - m[r];
                // fast path: one hw exp + one fma. |fast-exact| <= ~4e-5, guard 1.5e-4.
                float fastv = fmaf(__expf(es), crcp[r], za);
                float fr = fastv - floorf(fastv);
                if (fabsf(fr - 0.5f) < 1.5e-4f) {
                    // exact reference chain (bit-identical to jnp path)
                    float av = expf(es) / se[r];
                    fastv = av / sa + za;
                }
                float aqv = rintf(fastv);
                rs_a[r] += aqv;
                myAq[(quad * 4 + r) * 64 + t * 16 + col16] = (signed char)(int)aqv;
            }
        }
        asm volatile("s_waitcnt lgkmcnt(0)" ::: "memory");
        v4i pa = *(const v4i*)(myAq + col16 * 64 + quad * 16);
#pragma unroll
        for (int g = 0; g < 4; ++g) {
            v4i bv = *(const v4i*)(vbase + ((long)(g * 16 + col16)) * 1024 + ch * 64 + quad * 16);
            accPV[g] = __builtin_amdgcn_mfma_i32_16x16x64_i8(pa, bv, accPV[g], 0, 0, 0);
        }
        asm volatile("s_waitcnt lgkmcnt(0)" ::: "memory");
    }
#pragma unroll
    for (int r = 0; r < 4; ++r)
        for (int off = 1; off < 16; off <<= 1) rs_a[r] += __shfl_xor(rs_a[r], off);
    float sav = sa * sv;
    float zz = (za * zv) * 1024.0f;
    float vmn = INFINITY, vmx = -INFINITY;
#pragma unroll
    for (int g = 0; g < 4; ++g) {
        int d = g * 16 + col16;
        float cs = colsum_vq[bh * 64 + d] * za;
#pragma unroll
        for (int r = 0; r < 4; ++r) {
            int i = rowbase + quad * 4 + r;
            float v = ((float)accPV[g][r] - cs - rs_a[r] * zv + zz) * sav;
            out_mat[((long)b * Nn + i) * Dm + h * DH + d] = v;
            vmn = fminf(vmn, v); vmx = fmaxf(vmx, v);
        }
    }
    // fused P_O minmax
    red[tid] = vmx; __syncthreads();
    for (int s = 128; s > 0; s >>= 1) { if (tid < s) red[tid] = fmaxf(red[tid], red[tid + s]); __syncthreads(); }
    if (tid == 0) atomicMax(&scal[2 * P_O + 1], encf(red[0]));
    __syncthreads();
    red[tid] = vmn; __syncthreads();
    for (int s = 128; s > 0; s >>= 1) { if (tid < s) red[tid] = fminf(red[tid], red[tid + s]); __syncthreads(); }
    if (tid == 0) atomicMin(&scal[2 * P_O], encf(red[0]));
}

// ---------- launch ----------
extern "C" void kernel_launch(void* const* d_in, const int* in_sizes, int n_in,
                              void* d_out, int out_size, void* d_ws, size_t ws_size,
                              hipStream_t stream) {
    const float* x     = (const float*)d_in[0];
    const float* w_qkv = (const float*)d_in[1];
    const float* w_out = (const float*)d_in[2];
    const float* b_out = (const float*)d_in[3];

    char* ws = (char*)d_ws;
    size_t off = 0;
    auto alloc = [&](size_t n) -> char* {
        char* p = ws + off;
        off = (off + n + 255) & ~(size_t)255;
        return p;
    };
    unsigned*    scal        = (unsigned*)alloc(64);
    float*       xqkv        = (float*)alloc((size_t)Mm * I3 * 4);
    float*       out_mat     = (float*)alloc((size_t)Mm * Dm * 4);
    signed char* xq          = (signed char*)alloc((size_t)Mm * Dm);
    signed char* wq          = (signed char*)alloc((size_t)I3 * Dm);
    signed char* w2q         = (signed char*)alloc((size_t)Dm * Dm);
    signed char* oq          = (signed char*)alloc((size_t)Mm * Dm);
    signed char* qq          = (signed char*)alloc((size_t)BHt * Nn * DH);
    signed char* kq          = (signed char*)alloc((size_t)BHt * Nn * DH);
    signed char* vqT         = (signed char*)alloc((size_t)BHt * Nn * DH);
    float*       rowsum_xq   = (float*)alloc((size_t)Mm * 4);
    float*       colsum_w1   = (float*)alloc((size_t)I3 * 4);
    float*       colsum_w2   = (float*)alloc((size_t)Dm * 4);
    float*       rowsum_xqkv = (float*)alloc((size_t)Mm * 4);
    float*       rowsum_qq   = (float*)alloc((size_t)BHt * Nn * 4);
    float*       colsum_kq   = (float*)alloc((size_t)BHt * Nn * 4);
    float*       colsum_vq   = (float*)alloc((size_t)BHt * DH * 4);
    float*       rowmax      = (float*)alloc((size_t)BHt * Nn * 4);
    float*       sumexp      = (float*)alloc((size_t)BHt * Nn * 4);
    float*       oq_rowsum   = (float*)alloc((size_t)Mm * 4);

    k_init<<<16, 256, 0, stream>>>(scal, rowsum_xqkv, Mm);

    k_minmax3<<<448, 256, 0, stream>>>(x, w_qkv, w_out, scal);
    k_quant3<<<7168, 256, 0, stream>>>(x, w_qkv, w_out, scal, xq, wq, w2q,
                                       rowsum_xq, colsum_w1, colsum_w2);

    {   // GEMM1 + fused xqkv row sums and Q/K/V minmax
        dim3 g(I3 / 64, Mm / 128);
        k_gemm_mfma<<<g, 256, 0, stream>>>(xq, wq, colsum_w1, rowsum_xq, nullptr, xqkv,
                                           Dm, I3, scal, P_X, P_W1, 768.0f,
                                           1, rowsum_xqkv, scal);
    }

    k_quant_qkv<<<BHt * Nn, 64, 0, stream>>>(xqkv, scal, qq, kq, vqT, rowsum_qq, colsum_kq);
    k_colsum_vq<<<BHt * DH, 256, 0, stream>>>(vqT, colsum_vq);

    k_attn_a2<<<BHt * 16, 256, 0, stream>>>(qq, kq, rowsum_qq, colsum_kq, scal, rowmax, sumexp);
    k_attn_b2<<<BHt * 16, 256, 0, stream>>>(qq, kq, vqT, rowsum_qq, colsum_kq, colsum_vq,
                                            rowmax, sumexp, scal, out_mat);

    k_quant_rows<<<Mm, 256, 0, stream>>>(out_mat, scal, P_O, oq, oq_rowsum);

    {   // GEMM2 (+bias)
        dim3 g(Dm / 64, Mm / 128);
        k_gemm_mfma<<<g, 256, 0, stream>>>(oq, w2q, colsum_w2, rowsum_xqkv, b_out, (float*)d_out,
                                           Dm, Dm, scal, P_O, P_W2, 2304.0f,
                                           0, nullptr, nullptr);
    }
}

// Round 4
// 303.133 us; speedup vs baseline: 12.8994x; 1.1097x over previous
//
#include <hip/hip_runtime.h>
#include <math.h>

#define HEADS 12
#define DH    64
#define Dm    768
#define I3    2304
#define Nn    1024
#define Mm    4096
#define BHt   48

// minmax pair indices
#define P_X  0
#define P_W1 1
#define P_Q  2
#define P_K  3
#define P_V  4
#define P_A  5
#define P_O  6
#define P_W2 7

typedef int v4i __attribute__((ext_vector_type(4)));

// ---------- helpers ----------
__device__ inline unsigned encf(float f) {
    unsigned u = __float_as_uint(f);
    return (u & 0x80000000u) ? ~u : (u | 0x80000000u);
}
__device__ inline float decf(unsigned u) {
    return (u & 0x80000000u) ? __uint_as_float(u & 0x7fffffffu) : __uint_as_float(~u);
}
__device__ inline void get_sz(const unsigned* scal, int pair, float* s, float* z) {
    float mn = decf(scal[2 * pair]);
    float mx = decf(scal[2 * pair + 1]);
    float ss = (mx - mn) / 15.0f;
    *s = ss;
    *z = rintf(15.0f - mx / ss);
}

// ---------- kernels ----------
// init scal + zero rowsum_xqkv (4096 floats)
__global__ __launch_bounds__(256) void k_init(unsigned* scal, float* zbuf, int nz) {
    int g = blockIdx.x * 256 + threadIdx.x;
    if (g < nz) zbuf[g] = 0.f;
    if (g < 8) { scal[2 * g] = 0xFFFFFFFFu; scal[2 * g + 1] = 0u; }
}

// fused minmax of x (4096x768), w_qkv (2304x768), w_out (768x768); all cols=768
__global__ __launch_bounds__(256) void k_minmax3(const float* x, const float* w1, const float* w2,
                                                 unsigned* scal) {
    __shared__ float rmn[256], rmx[256];
    int bid = blockIdx.x, tid = threadIdx.x;
    const float* src; int rows, pair, b0, nb;
    if (bid < 256)      { src = x;  rows = 4096; pair = P_X;  b0 = 0;   nb = 256; }
    else if (bid < 384) { src = w1; rows = 2304; pair = P_W1; b0 = 256; nb = 128; }
    else                { src = w2; rows = 768;  pair = P_W2; b0 = 384; nb = 64;  }
    float mn = INFINITY, mx = -INFINITY;
    for (int r = bid - b0; r < rows; r += nb) {
        const float* row = src + (long)r * 768;
#pragma unroll
        for (int k = 0; k < 3; ++k) {
            float v = row[tid + k * 256];
            mn = fminf(mn, v); mx = fmaxf(mx, v);
        }
    }
    rmn[tid] = mn; rmx[tid] = mx; __syncthreads();
    for (int s = 128; s > 0; s >>= 1) {
        if (tid < s) { rmn[tid] = fminf(rmn[tid], rmn[tid + s]); rmx[tid] = fmaxf(rmx[tid], rmx[tid + s]); }
        __syncthreads();
    }
    if (tid == 0) {
        atomicMin(&scal[2 * pair], encf(rmn[0]));
        atomicMax(&scal[2 * pair + 1], encf(rmx[0]));
    }
}

// fused quantization of x / w_qkv / w_out (cols=768) -> int8 + row sums
__global__ __launch_bounds__(256) void k_quant3(const float* x, const float* w1, const float* w2,
                                                const unsigned* scal,
                                                signed char* xq, signed char* wq, signed char* w2q,
                                                float* rs_x, float* rs_w1, float* rs_w2) {
    __shared__ float red[256];
    int bid = blockIdx.x, tid = threadIdx.x;
    const float* src; signed char* dq; float* rs; int pair, r;
    if (bid < 4096)      { src = x;  dq = xq;  rs = rs_x;  pair = P_X;  r = bid; }
    else if (bid < 6400) { src = w1; dq = wq;  rs = rs_w1; pair = P_W1; r = bid - 4096; }
    else                 { src = w2; dq = w2q; rs = rs_w2; pair = P_W2; r = bid - 6400; }
    float s, z; get_sz(scal, pair, &s, &z);
    const float* row = src + (long)r * 768;
    signed char* drow = dq + (long)r * 768;
    float acc = 0.f;
#pragma unroll
    for (int k = 0; k < 3; ++k) {
        int c = tid + k * 256;
        float q = rintf(row[c] / s + z);
        drow[c] = (signed char)(int)q;
        acc += q;
    }
    red[tid] = acc; __syncthreads();
    for (int s2 = 128; s2 > 0; s2 >>= 1) { if (tid < s2) red[tid] += red[tid + s2]; __syncthreads(); }
    if (tid == 0) rs[r] = red[0];
}

// single-array quant (for out_mat -> oq), cols=768
__global__ __launch_bounds__(256) void k_quant_rows(const float* src, const unsigned* scal, int pair,
                                                    signed char* dq, float* rowsum) {
    __shared__ float red[256];
    int r = blockIdx.x, tid = threadIdx.x;
    float s, z; get_sz(scal, pair, &s, &z);
    const float* row = src + (long)r * 768;
    signed char* drow = dq + (long)r * 768;
    float acc = 0.f;
#pragma unroll
    for (int k = 0; k < 3; ++k) {
        int c = tid + k * 256;
        float q = rintf(row[c] / s + z);
        drow[c] = (signed char)(int)q;
        acc += q;
    }
    red[tid] = acc; __syncthreads();
    for (int s2 = 128; s2 > 0; s2 >>= 1) { if (tid < s2) red[tid] += red[tid + s2]; __syncthreads(); }
    if (tid == 0) rowsum[r] = red[0];
}

// MFMA int8 GEMM, block tile 128x128, BK=64 bytes, LDS-staged with register double-buffer.
// LDS layout (fragment-contiguous swizzle): byte(row, k) at
//   (row>>4)*1024 + (k>>4)*256 + (row&15)*16 + (k&15)
// so each ds_read_b128 frag (16 lanes x 16B) is one contiguous 256B chunk.
// C[i,j] = (acc - colsumB[j]*zA - rowsumA[i]*zB + zA*zB*corrK)*(sA*sB) (+bias)
// do_stats: atomicAdd per-row sums of C into rowsum_out + global minmax of C into
// scal_mm pair P_Q + colbase/768 (GEMM1 -> xqkv stats fusion; 768 % TN == 0).
__global__ __launch_bounds__(256) void k_gemm_mfma(const signed char* A, const signed char* B,
                                                   const float* colsumB, const float* rowsumA,
                                                   const float* bias, float* C, int K, int ldC,
                                                   const unsigned* scal, int pairA, int pairB,
                                                   float corrK, int do_stats, float* rowsum_out,
                                                   unsigned* scal_mm) {
    __shared__ __align__(16) signed char As[128 * 64];
    __shared__ __align__(16) signed char Bs[128 * 64];
    __shared__ float red[256];
    int tid = threadIdx.x;
    int wave = tid >> 6, lane = tid & 63;
    int col16 = lane & 15, quad = lane >> 4;
    long rowbase = (long)blockIdx.y * 128;
    long colbase = (long)blockIdx.x * 128;

    // staging: thread t covers (row=t>>2 and t>>2+64, k-chunk=t&3) for both A and B
    int c4 = tid & 3, r4 = tid >> 2;                 // r4 in 0..63
    const signed char* ag0 = A + (rowbase + r4) * K + c4 * 16;
    const signed char* ag1 = A + (rowbase + r4 + 64) * K + c4 * 16;
    const signed char* bg0 = B + (colbase + r4) * K + c4 * 16;
    const signed char* bg1 = B + (colbase + r4 + 64) * K + c4 * 16;
    int soff0 = ((r4 >> 4) << 10) + (c4 << 8) + ((r4 & 15) << 4);
    int soff1 = soff0 + 4096;                        // rows +64 -> rg +4

    v4i ra0 = *(const v4i*)ag0;
    v4i ra1 = *(const v4i*)ag1;
    v4i rb0 = *(const v4i*)bg0;
    v4i rb1 = *(const v4i*)bg1;

    const int afrag_off = wave * 2048 + quad * 256 + col16 * 16;   // rg = 2*wave (+1)
    const int bfrag_off = quad * 256 + col16 * 16;                 // rg = g
    v4i acc[2][8] = {};
    int nk = K >> 6;
    for (int kt = 0; kt < nk; ++kt) {
        *(v4i*)(As + soff0) = ra0;
        *(v4i*)(As + soff1) = ra1;
        *(v4i*)(Bs + soff0) = rb0;
        *(v4i*)(Bs + soff1) = rb1;
        __syncthreads();
        if (kt + 1 < nk) {
            int ko = (kt + 1) << 6;
            ra0 = *(const v4i*)(ag0 + ko);
            ra1 = *(const v4i*)(ag1 + ko);
            rb0 = *(const v4i*)(bg0 + ko);
            rb1 = *(const v4i*)(bg1 + ko);
        }
        v4i af0 = *(const v4i*)(As + afrag_off);
        v4i af1 = *(const v4i*)(As + afrag_off + 1024);
        v4i bf[8];
#pragma unroll
        for (int g = 0; g < 8; ++g) bf[g] = *(const v4i*)(Bs + bfrag_off + g * 1024);
#pragma unroll
        for (int g = 0; g < 8; ++g) {
            acc[0][g] = __builtin_amdgcn_mfma_i32_16x16x64_i8(af0, bf[g], acc[0][g], 0, 0, 0);
            acc[1][g] = __builtin_amdgcn_mfma_i32_16x16x64_i8(af1, bf[g], acc[1][g], 0, 0, 0);
        }
        __syncthreads();
    }

    float sA, zA, sB, zB;
    get_sz(scal, pairA, &sA, &zA);
    get_sz(scal, pairB, &sB, &zB);
    float sAB = sA * sB;
    float zz = (zA * zB) * corrK;
    float vmn = INFINITY, vmx = -INFINITY;
    float rowpart[2][4] = {};
#pragma unroll
    for (int i2 = 0; i2 < 2; ++i2)
#pragma unroll
        for (int g = 0; g < 8; ++g) {
            long col = colbase + g * 16 + col16;
            float cs = colsumB[col] * zA;
            float bv = bias ? bias[col] : 0.f;
#pragma unroll
            for (int r = 0; r < 4; ++r) {
                long row = rowbase + wave * 32 + i2 * 16 + quad * 4 + r;
                float v = ((float)acc[i2][g][r] - cs - rowsumA[row] * zB + zz) * sAB + bv;
                C[row * ldC + col] = v;
                rowpart[i2][r] += v;
                vmn = fminf(vmn, v); vmx = fmaxf(vmx, v);
            }
        }
    if (do_stats) {
#pragma unroll
        for (int i2 = 0; i2 < 2; ++i2)
#pragma unroll
            for (int r = 0; r < 4; ++r) {
                float s = rowpart[i2][r];
                s += __shfl_xor(s, 1); s += __shfl_xor(s, 2);
                s += __shfl_xor(s, 4); s += __shfl_xor(s, 8);
                if (col16 == 0)
                    atomicAdd(&rowsum_out[rowbase + wave * 32 + i2 * 16 + quad * 4 + r], s);
            }
        int pair = P_Q + (int)(colbase / 768);
        red[tid] = vmx; __syncthreads();
        for (int s = 128; s > 0; s >>= 1) { if (tid < s) red[tid] = fmaxf(red[tid], red[tid + s]); __syncthreads(); }
        if (tid == 0) atomicMax(&scal_mm[2 * pair + 1], encf(red[0]));
        __syncthreads();
        red[tid] = vmn; __syncthreads();
        for (int s = 128; s > 0; s >>= 1) { if (tid < s) red[tid] = fminf(red[tid], red[tid + s]); __syncthreads(); }
        if (tid == 0) atomicMin(&scal_mm[2 * pair], encf(red[0]));
    }
}

// quantize q/k/v. qq,kq: [bh][i][d] (row-contig). vqT: [bh][d][i] (d-major). Row sums for qq, kq.
__global__ __launch_bounds__(64) void k_quant_qkv(const float* xqkv, const unsigned* scal,
                                                  signed char* qq, signed char* kq, signed char* vqT,
                                                  float* rowsum_qq, float* colsum_kq) {
    int blk = blockIdx.x;
    int bh = blk >> 10, i = blk & 1023;
    int d = threadIdx.x;
    int b = bh / HEADS, h = bh - HEADS * b;
    const float* row = xqkv + ((long)b * Nn + i) * I3 + h * DH;
    float sq, zq, sk, zk, sv, zv;
    get_sz(scal, P_Q, &sq, &zq);
    get_sz(scal, P_K, &sk, &zk);
    get_sz(scal, P_V, &sv, &zv);
    float q = rintf(row[d] / sq + zq);
    float k = rintf(row[768 + d] / sk + zk);
    float v = rintf(row[1536 + d] / sv + zv);
    long o = (long)blk * 64 + d;
    qq[o] = (signed char)(int)q;
    kq[o] = (signed char)(int)k;
    vqT[((long)bh * 64 + d) * 1024 + i] = (signed char)(int)v;
    float s1 = q, s2 = k;
    for (int off = 32; off > 0; off >>= 1) {
        s1 += __shfl_down(s1, off);
        s2 += __shfl_down(s2, off);
    }
    if (d == 0) { rowsum_qq[blk] = s1; colsum_kq[blk] = s2; }
}

// column sums of V (over keys j) from vqT rows — contiguous reads
__global__ __launch_bounds__(256) void k_colsum_vq(const signed char* vqT, float* colsum) {
    __shared__ float red[256];
    int tid = threadIdx.x;
    const signed char* row = vqT + (long)blockIdx.x * 1024;
    float acc = 0.f;
    for (int j = tid; j < Nn; j += 256) acc += (float)row[j];
    red[tid] = acc; __syncthreads();
    for (int s = 128; s > 0; s >>= 1) { if (tid < s) red[tid] += red[tid + s]; __syncthreads(); }
    if (tid == 0) colsum[blockIdx.x] = red[0];
}

// Pass A (MFMA): per block 64 Q-rows (4 waves x 16). Sweep1: row max/min of dots. Sweep2: sumexp.
__global__ __launch_bounds__(256) void k_attn_a2(const signed char* qq, const signed char* kq,
                                                 const float* rowsum_qq, const float* colsum_kq,
                                                 unsigned* scal, float* rowmax, float* sumexp) {
    __shared__ float redm[256];
    int blk = blockIdx.x;               // 48 bh * 16 itiles
    int bh = blk >> 4, itile = blk & 15;
    int tid = threadIdx.x;
    int wave = tid >> 6, lane = tid & 63;
    int col16 = lane & 15, quad = lane >> 4;
    int rowbase = itile * 64 + wave * 16;  // within bh
    const signed char* kbase = kq + (long)bh * Nn * 64;
    const float* csk_base = colsum_kq + bh * Nn;
    v4i afrag = *(const v4i*)(qq + ((long)bh * Nn + rowbase + col16) * 64 + quad * 16);
    float sq, zq, sk, zk;
    get_sz(scal, P_Q, &sq, &zq);
    get_sz(scal, P_K, &sk, &zk);
    float csc = (0.125f * sq) * sk;
    float rsq[4];
#pragma unroll
    for (int r = 0; r < 4; ++r) rsq[r] = rowsum_qq[bh * Nn + rowbase + quad * 4 + r];
    float lmax[4] = {-INFINITY, -INFINITY, -INFINITY, -INFINITY};
    float lmin[4] = {INFINITY, INFINITY, INFINITY, INFINITY};
    v4i zero = {0, 0, 0, 0};
    for (int jt = 0; jt < 64; ++jt) {
        v4i bfrag = *(const v4i*)(kbase + (long)(jt * 16 + col16) * 64 + quad * 16);
        v4i d = __builtin_amdgcn_mfma_i32_16x16x64_i8(afrag, bfrag, zero, 0, 0, 0);
        float csk = csk_base[jt * 16 + col16] * zq;
#pragma unroll
        for (int r = 0; r < 4; ++r) {
            float dv = ((float)d[r] - csk - rsq[r] * zk) * csc;
            lmax[r] = fmaxf(lmax[r], dv);
            lmin[r] = fminf(lmin[r], dv);
        }
    }
#pragma unroll
    for (int r = 0; r < 4; ++r) {
        for (int off = 1; off < 16; off <<= 1) {
            lmax[r] = fmaxf(lmax[r], __shfl_xor(lmax[r], off));
            lmin[r] = fminf(lmin[r], __shfl_xor(lmin[r], off));
        }
    }
    float se[4] = {0.f, 0.f, 0.f, 0.f};
    for (int jt = 0; jt < 64; ++jt) {
        v4i bfrag = *(const v4i*)(kbase + (long)(jt * 16 + col16) * 64 + quad * 16);
        v4i d = __builtin_amdgcn_mfma_i32_16x16x64_i8(afrag, bfrag, zero, 0, 0, 0);
        float csk = csk_base[jt * 16 + col16] * zq;
#pragma unroll
        for (int r = 0; r < 4; ++r) {
            float dv = ((float)d[r] - csk - rsq[r] * zk) * csc;
            se[r] += expf(dv - lmax[r]);
        }
    }
#pragma unroll
    for (int r = 0; r < 4; ++r)
        for (int off = 1; off < 16; off <<= 1) se[r] += __shfl_xor(se[r], off);
    float amax_c = -INFINITY, amin_c = INFINITY;
    if (col16 == 0) {
#pragma unroll
        for (int r = 0; r < 4; ++r) {
            int row = bh * Nn + rowbase + quad * 4 + r;
            rowmax[row] = lmax[r];
            sumexp[row] = se[r];
            amax_c = fmaxf(amax_c, 1.0f / se[r]);
            amin_c = fminf(amin_c, expf(lmin[r] - lmax[r]) / se[r]);
        }
    }
    redm[tid] = amax_c; __syncthreads();
    for (int s = 128; s > 0; s >>= 1) { if (tid < s) redm[tid] = fmaxf(redm[tid], redm[tid + s]); __syncthreads(); }
    if (tid == 0) atomicMax(&scal[2 * P_A + 1], encf(redm[0]));
    __syncthreads();
    redm[tid] = amin_c; __syncthreads();
    for (int s = 128; s > 0; s >>= 1) { if (tid < s) redm[tid] = fminf(redm[tid], redm[tid + s]); __syncthreads(); }
    if (tid == 0) atomicMin(&scal[2 * P_A], encf(redm[0]));
}

// Pass B (MFMA): recompute dots, quantize a (fast path + exact-fallback guard, bit-identical
// to the exact chain), LDS C->A relayout per wave, PV via MFMA vs vqT. Fused P_O minmax.
__global__ __launch_bounds__(256) void k_attn_b2(const signed char* qq, const signed char* kq,
                                                 const signed char* vqT, const float* rowsum_qq,
                                                 const float* colsum_kq, const float* colsum_vq,
                                                 const float* rowmax, const float* sumexp,
                                                 unsigned* scal, float* out_mat) {
    __shared__ __align__(16) signed char Aq[4][16 * 64];
    __shared__ float red[256];
    int blk = blockIdx.x;
    int bh = blk >> 4, itile = blk & 15;
    int tid = threadIdx.x;
    int wave = tid >> 6, lane = tid & 63;
    int col16 = lane & 15, quad = lane >> 4;
    int rowbase = itile * 64 + wave * 16;
    int b = bh / HEADS, h = bh - HEADS * b;
    const signed char* kbase = kq + (long)bh * Nn * 64;
    const signed char* vbase = vqT + (long)bh * 64 * 1024;
    const float* csk_base = colsum_kq + bh * Nn;
    v4i afrag = *(const v4i*)(qq + ((long)bh * Nn + rowbase + col16) * 64 + quad * 16);
    float sq, zq, sk, zk, sv, zv, sa, za;
    get_sz(scal, P_Q, &sq, &zq);
    get_sz(scal, P_K, &sk, &zk);
    get_sz(scal, P_V, &sv, &zv);
    get_sz(scal, P_A, &sa, &za);
    float csc = (0.125f * sq) * sk;
    float rsq[4], m[4], se[4], crcp[4];
#pragma unroll
    for (int r = 0; r < 4; ++r) {
        int row = bh * Nn + rowbase + quad * 4 + r;
        rsq[r] = rowsum_qq[row];
        m[r] = rowmax[row];
        se[r] = sumexp[row];
        crcp[r] = 1.0f / (se[r] * sa);   // fast-path scale; guarded below
    }
    signed char* myAq = Aq[wave];
    v4i accPV[4] = {};
    float rs_a[4] = {0.f, 0.f, 0.f, 0.f};
    v4i zero = {0, 0, 0, 0};
    for (int ch = 0; ch < 16; ++ch) {
#pragma unroll
        for (int t = 0; t < 4; ++t) {
            int jt = ch * 4 + t;
            v4i bfrag = *(const v4i*)(kbase + (long)(jt * 16 + col16) * 64 + quad * 16);
            v4i d = __builtin_amdgcn_mfma_i32_16x16x64_i8(afrag, bfrag, zero, 0, 0, 0);
            float csk = csk_base[jt * 16 + col16] * zq;
#pragma unroll
            for (int r = 0; r < 4; ++r) {
                float dv = ((float)d[r] - csk - rsq[r] * zk) * csc;
                float es = dv - m[r];
                // fast path: one hw exp + one fma. |fast-exact| <= ~4e-5, guard 1.5e-4.
                float fastv = fmaf(__expf(es), crcp[r], za);
                float fr = fastv - floorf(fastv);
                if (fabsf(fr - 0.5f) < 1.5e-4f) {
                    // exact reference chain (bit-identical to jnp path)
                    float av = expf(es) / se[r];
                    fastv = av / sa + za;
                }
                float aqv = rintf(fastv);
                rs_a[r] += aqv;
                myAq[(quad * 4 + r) * 64 + t * 16 + col16] = (signed char)(int)aqv;
            }
        }
        asm volatile("s_waitcnt lgkmcnt(0)" ::: "memory");
        v4i pa = *(const v4i*)(myAq + col16 * 64 + quad * 16);
#pragma unroll
        for (int g = 0; g < 4; ++g) {
            v4i bv = *(const v4i*)(vbase + ((long)(g * 16 + col16)) * 1024 + ch * 64 + quad * 16);
            accPV[g] = __builtin_amdgcn_mfma_i32_16x16x64_i8(pa, bv, accPV[g], 0, 0, 0);
        }
        asm volatile("s_waitcnt lgkmcnt(0)" ::: "memory");
    }
#pragma unroll
    for (int r = 0; r < 4; ++r)
        for (int off = 1; off < 16; off <<= 1) rs_a[r] += __shfl_xor(rs_a[r], off);
    float sav = sa * sv;
    float zz = (za * zv) * 1024.0f;
    float vmn = INFINITY, vmx = -INFINITY;
#pragma unroll
    for (int g = 0; g < 4; ++g) {
        int d = g * 16 + col16;
        float cs = colsum_vq[bh * 64 + d] * za;
#pragma unroll
        for (int r = 0; r < 4; ++r) {
            int i = rowbase + quad * 4 + r;
            float v = ((float)accPV[g][r] - cs - rs_a[r] * zv + zz) * sav;
            out_mat[((long)b * Nn + i) * Dm + h * DH + d] = v;
            vmn = fminf(vmn, v); vmx = fmaxf(vmx, v);
        }
    }
    // fused P_O minmax
    red[tid] = vmx; __syncthreads();
    for (int s = 128; s > 0; s >>= 1) { if (tid < s) red[tid] = fmaxf(red[tid], red[tid + s]); __syncthreads(); }
    if (tid == 0) atomicMax(&scal[2 * P_O + 1], encf(red[0]));
    __syncthreads();
    red[tid] = vmn; __syncthreads();
    for (int s = 128; s > 0; s >>= 1) { if (tid < s) red[tid] = fminf(red[tid], red[tid + s]); __syncthreads(); }
    if (tid == 0) atomicMin(&scal[2 * P_O], encf(red[0]));
}

// ---------- launch ----------
extern "C" void kernel_launch(void* const* d_in, const int* in_sizes, int n_in,
                              void* d_out, int out_size, void* d_ws, size_t ws_size,
                              hipStream_t stream) {
    const float* x     = (const float*)d_in[0];
    const float* w_qkv = (const float*)d_in[1];
    const float* w_out = (const float*)d_in[2];
    const float* b_out = (const float*)d_in[3];

    char* ws = (char*)d_ws;
    size_t off = 0;
    auto alloc = [&](size_t n) -> char* {
        char* p = ws + off;
        off = (off + n + 255) & ~(size_t)255;
        return p;
    };
    unsigned*    scal        = (unsigned*)alloc(64);
    float*       xqkv        = (float*)alloc((size_t)Mm * I3 * 4);
    float*       out_mat     = (float*)alloc((size_t)Mm * Dm * 4);
    signed char* xq          = (signed char*)alloc((size_t)Mm * Dm);
    signed char* wq          = (signed char*)alloc((size_t)I3 * Dm);
    signed char* w2q         = (signed char*)alloc((size_t)Dm * Dm);
    signed char* oq          = (signed char*)alloc((size_t)Mm * Dm);
    signed char* qq          = (signed char*)alloc((size_t)BHt * Nn * DH);
    signed char* kq          = (signed char*)alloc((size_t)BHt * Nn * DH);
    signed char* vqT         = (signed char*)alloc((size_t)BHt * Nn * DH);
    float*       rowsum_xq   = (float*)alloc((size_t)Mm * 4);
    float*       colsum_w1   = (float*)alloc((size_t)I3 * 4);
    float*       colsum_w2   = (float*)alloc((size_t)Dm * 4);
    float*       rowsum_xqkv = (float*)alloc((size_t)Mm * 4);
    float*       rowsum_qq   = (float*)alloc((size_t)BHt * Nn * 4);
    float*       colsum_kq   = (float*)alloc((size_t)BHt * Nn * 4);
    float*       colsum_vq   = (float*)alloc((size_t)BHt * DH * 4);
    float*       rowmax      = (float*)alloc((size_t)BHt * Nn * 4);
    float*       sumexp      = (float*)alloc((size_t)BHt * Nn * 4);
    float*       oq_rowsum   = (float*)alloc((size_t)Mm * 4);

    k_init<<<16, 256, 0, stream>>>(scal, rowsum_xqkv, Mm);

    k_minmax3<<<448, 256, 0, stream>>>(x, w_qkv, w_out, scal);
    k_quant3<<<7168, 256, 0, stream>>>(x, w_qkv, w_out, scal, xq, wq, w2q,
                                       rowsum_xq, colsum_w1, colsum_w2);

    {   // GEMM1 + fused xqkv row sums and Q/K/V minmax
        dim3 g(I3 / 128, Mm / 128);
        k_gemm_mfma<<<g, 256, 0, stream>>>(xq, wq, colsum_w1, rowsum_xq, nullptr, xqkv,
                                           Dm, I3, scal, P_X, P_W1, 768.0f,
                                           1, rowsum_xqkv, scal);
    }

    k_quant_qkv<<<BHt * Nn, 64, 0, stream>>>(xqkv, scal, qq, kq, vqT, rowsum_qq, colsum_kq);
    k_colsum_vq<<<BHt * DH, 256, 0, stream>>>(vqT, colsum_vq);

    k_attn_a2<<<BHt * 16, 256, 0, stream>>>(qq, kq, rowsum_qq, colsum_kq, scal, rowmax, sumexp);
    k_attn_b2<<<BHt * 16, 256, 0, stream>>>(qq, kq, vqT, rowsum_qq, colsum_kq, colsum_vq,
                                            rowmax, sumexp, scal, out_mat);

    k_quant_rows<<<Mm, 256, 0, stream>>>(out_mat, scal, P_O, oq, oq_rowsum);

    {   // GEMM2 (+bias)
        dim3 g(Dm / 128, Mm / 128);
        k_gemm_mfma<<<g, 256, 0, stream>>>(oq, w2q, colsum_w2, rowsum_xqkv, b_out, (float*)d_out,
                                           Dm, Dm, scal, P_O, P_W2, 2304.0f,
                                           0, nullptr, nullptr);
    }
}

// Round 5
// 298.278 us; speedup vs baseline: 13.1093x; 1.0163x over previous
//
#include <hip/hip_runtime.h>
#include <math.h>

#define HEADS 12
#define DH    64
#define Dm    768
#define I3    2304
#define Nn    1024
#define Mm    4096
#define BHt   48

// minmax pair indices
#define P_X  0
#define P_W1 1
#define P_Q  2
#define P_K  3
#define P_V  4
#define P_A  5
#define P_O  6
#define P_W2 7

typedef int v4i __attribute__((ext_vector_type(4)));

// ---------- helpers ----------
__device__ inline unsigned encf(float f) {
    unsigned u = __float_as_uint(f);
    return (u & 0x80000000u) ? ~u : (u | 0x80000000u);
}
__device__ inline float decf(unsigned u) {
    return (u & 0x80000000u) ? __uint_as_float(u & 0x7fffffffu) : __uint_as_float(~u);
}
__device__ inline void get_sz(const unsigned* scal, int pair, float* s, float* z) {
    float mn = decf(scal[2 * pair]);
    float mx = decf(scal[2 * pair + 1]);
    float ss = (mx - mn) / 15.0f;
    *s = ss;
    *z = rintf(15.0f - mx / ss);
}

// ---------- kernels ----------
__global__ __launch_bounds__(256) void k_init(unsigned* scal, float* zbuf, int nz) {
    int g = blockIdx.x * 256 + threadIdx.x;
    if (g < nz) zbuf[g] = 0.f;
    if (g < 8) { scal[2 * g] = 0xFFFFFFFFu; scal[2 * g + 1] = 0u; }
}

// fused minmax of x (4096x768), w_qkv (2304x768), w_out (768x768); all cols=768
__global__ __launch_bounds__(256) void k_minmax3(const float* x, const float* w1, const float* w2,
                                                 unsigned* scal) {
    __shared__ float rmn[256], rmx[256];
    int bid = blockIdx.x, tid = threadIdx.x;
    const float* src; int rows, pair, b0, nb;
    if (bid < 256)      { src = x;  rows = 4096; pair = P_X;  b0 = 0;   nb = 256; }
    else if (bid < 384) { src = w1; rows = 2304; pair = P_W1; b0 = 256; nb = 128; }
    else                { src = w2; rows = 768;  pair = P_W2; b0 = 384; nb = 64;  }
    float mn = INFINITY, mx = -INFINITY;
    for (int r = bid - b0; r < rows; r += nb) {
        const float* row = src + (long)r * 768;
#pragma unroll
        for (int k = 0; k < 3; ++k) {
            float v = row[tid + k * 256];
            mn = fminf(mn, v); mx = fmaxf(mx, v);
        }
    }
    rmn[tid] = mn; rmx[tid] = mx; __syncthreads();
    for (int s = 128; s > 0; s >>= 1) {
        if (tid < s) { rmn[tid] = fminf(rmn[tid], rmn[tid + s]); rmx[tid] = fmaxf(rmx[tid], rmx[tid + s]); }
        __syncthreads();
    }
    if (tid == 0) {
        atomicMin(&scal[2 * pair], encf(rmn[0]));
        atomicMax(&scal[2 * pair + 1], encf(rmx[0]));
    }
}

// fused quantization of x / w_qkv / w_out (cols=768) -> int8 + row sums
__global__ __launch_bounds__(256) void k_quant3(const float* x, const float* w1, const float* w2,
                                                const unsigned* scal,
                                                signed char* xq, signed char* wq, signed char* w2q,
                                                float* rs_x, float* rs_w1, float* rs_w2) {
    __shared__ float red[256];
    int bid = blockIdx.x, tid = threadIdx.x;
    const float* src; signed char* dq; float* rs; int pair, r;
    if (bid < 4096)      { src = x;  dq = xq;  rs = rs_x;  pair = P_X;  r = bid; }
    else if (bid < 6400) { src = w1; dq = wq;  rs = rs_w1; pair = P_W1; r = bid - 4096; }
    else                 { src = w2; dq = w2q; rs = rs_w2; pair = P_W2; r = bid - 6400; }
    float s, z; get_sz(scal, pair, &s, &z);
    const float* row = src + (long)r * 768;
    signed char* drow = dq + (long)r * 768;
    float acc = 0.f;
#pragma unroll
    for (int k = 0; k < 3; ++k) {
        int c = tid + k * 256;
        float q = rintf(row[c] / s + z);
        drow[c] = (signed char)(int)q;
        acc += q;
    }
    red[tid] = acc; __syncthreads();
    for (int s2 = 128; s2 > 0; s2 >>= 1) { if (tid < s2) red[tid] += red[tid + s2]; __syncthreads(); }
    if (tid == 0) rs[r] = red[0];
}

// single-array quant (for out_mat -> oq), cols=768
__global__ __launch_bounds__(256) void k_quant_rows(const float* src, const unsigned* scal, int pair,
                                                    signed char* dq, float* rowsum) {
    __shared__ float red[256];
    int r = blockIdx.x, tid = threadIdx.x;
    float s, z; get_sz(scal, pair, &s, &z);
    const float* row = src + (long)r * 768;
    signed char* drow = dq + (long)r * 768;
    float acc = 0.f;
#pragma unroll
    for (int k = 0; k < 3; ++k) {
        int c = tid + k * 256;
        float q = rintf(row[c] / s + z);
        drow[c] = (signed char)(int)q;
        acc += q;
    }
    red[tid] = acc; __syncthreads();
    for (int s2 = 128; s2 > 0; s2 >>= 1) { if (tid < s2) red[tid] += red[tid + s2]; __syncthreads(); }
    if (tid == 0) rowsum[r] = red[0];
}

// MFMA int8 GEMM, block tile 128x128, BK=64 bytes, LDS-staged with register double-buffer.
__global__ __launch_bounds__(256) void k_gemm_mfma(const signed char* A, const signed char* B,
                                                   const float* colsumB, const float* rowsumA,
                                                   const float* bias, float* C, int K, int ldC,
                                                   const unsigned* scal, int pairA, int pairB,
                                                   float corrK, int do_stats, float* rowsum_out,
                                                   unsigned* scal_mm) {
    __shared__ __align__(16) signed char As[128 * 64];
    __shared__ __align__(16) signed char Bs[128 * 64];
    __shared__ float red[256];
    int tid = threadIdx.x;
    int wave = tid >> 6, lane = tid & 63;
    int col16 = lane & 15, quad = lane >> 4;
    long rowbase = (long)blockIdx.y * 128;
    long colbase = (long)blockIdx.x * 128;

    int c4 = tid & 3, r4 = tid >> 2;
    const signed char* ag0 = A + (rowbase + r4) * K + c4 * 16;
    const signed char* ag1 = A + (rowbase + r4 + 64) * K + c4 * 16;
    const signed char* bg0 = B + (colbase + r4) * K + c4 * 16;
    const signed char* bg1 = B + (colbase + r4 + 64) * K + c4 * 16;
    int soff0 = ((r4 >> 4) << 10) + (c4 << 8) + ((r4 & 15) << 4);
    int soff1 = soff0 + 4096;

    v4i ra0 = *(const v4i*)ag0;
    v4i ra1 = *(const v4i*)ag1;
    v4i rb0 = *(const v4i*)bg0;
    v4i rb1 = *(const v4i*)bg1;

    const int afrag_off = wave * 2048 + quad * 256 + col16 * 16;
    const int bfrag_off = quad * 256 + col16 * 16;
    v4i acc[2][8] = {};
    int nk = K >> 6;
    for (int kt = 0; kt < nk; ++kt) {
        *(v4i*)(As + soff0) = ra0;
        *(v4i*)(As + soff1) = ra1;
        *(v4i*)(Bs + soff0) = rb0;
        *(v4i*)(Bs + soff1) = rb1;
        __syncthreads();
        if (kt + 1 < nk) {
            int ko = (kt + 1) << 6;
            ra0 = *(const v4i*)(ag0 + ko);
            ra1 = *(const v4i*)(ag1 + ko);
            rb0 = *(const v4i*)(bg0 + ko);
            rb1 = *(const v4i*)(bg1 + ko);
        }
        v4i af0 = *(const v4i*)(As + afrag_off);
        v4i af1 = *(const v4i*)(As + afrag_off + 1024);
        v4i bf[8];
#pragma unroll
        for (int g = 0; g < 8; ++g) bf[g] = *(const v4i*)(Bs + bfrag_off + g * 1024);
#pragma unroll
        for (int g = 0; g < 8; ++g) {
            acc[0][g] = __builtin_amdgcn_mfma_i32_16x16x64_i8(af0, bf[g], acc[0][g], 0, 0, 0);
            acc[1][g] = __builtin_amdgcn_mfma_i32_16x16x64_i8(af1, bf[g], acc[1][g], 0, 0, 0);
        }
        __syncthreads();
    }

    float sA, zA, sB, zB;
    get_sz(scal, pairA, &sA, &zA);
    get_sz(scal, pairB, &sB, &zB);
    float sAB = sA * sB;
    float zz = (zA * zB) * corrK;
    float vmn = INFINITY, vmx = -INFINITY;
    float rowpart[2][4] = {};
#pragma unroll
    for (int i2 = 0; i2 < 2; ++i2)
#pragma unroll
        for (int g = 0; g < 8; ++g) {
            long col = colbase + g * 16 + col16;
            float cs = colsumB[col] * zA;
            float bv = bias ? bias[col] : 0.f;
#pragma unroll
            for (int r = 0; r < 4; ++r) {
                long row = rowbase + wave * 32 + i2 * 16 + quad * 4 + r;
                float v = ((float)acc[i2][g][r] - cs - rowsumA[row] * zB + zz) * sAB + bv;
                C[row * ldC + col] = v;
                rowpart[i2][r] += v;
                vmn = fminf(vmn, v); vmx = fmaxf(vmx, v);
            }
        }
    if (do_stats) {
#pragma unroll
        for (int i2 = 0; i2 < 2; ++i2)
#pragma unroll
            for (int r = 0; r < 4; ++r) {
                float s = rowpart[i2][r];
                s += __shfl_xor(s, 1); s += __shfl_xor(s, 2);
                s += __shfl_xor(s, 4); s += __shfl_xor(s, 8);
                if (col16 == 0)
                    atomicAdd(&rowsum_out[rowbase + wave * 32 + i2 * 16 + quad * 4 + r], s);
            }
        int pair = P_Q + (int)(colbase / 768);
        red[tid] = vmx; __syncthreads();
        for (int s = 128; s > 0; s >>= 1) { if (tid < s) red[tid] = fmaxf(red[tid], red[tid + s]); __syncthreads(); }
        if (tid == 0) atomicMax(&scal_mm[2 * pair + 1], encf(red[0]));
        __syncthreads();
        red[tid] = vmn; __syncthreads();
        for (int s = 128; s > 0; s >>= 1) { if (tid < s) red[tid] = fminf(red[tid], red[tid + s]); __syncthreads(); }
        if (tid == 0) atomicMin(&scal_mm[2 * pair], encf(red[0]));
    }
}

// quantize q/k/v. qq,kq: [bh][i][d]. vqT: [bh][d][i]. Row sums for qq, kq. 4 i's per block.
__global__ __launch_bounds__(256) void k_quant_qkv(const float* xqkv, const unsigned* scal,
                                                   signed char* qq, signed char* kq, signed char* vqT,
                                                   float* rowsum_qq, float* colsum_kq) {
    int tid = threadIdx.x;
    int wave = tid >> 6, d = tid & 63;
    int base = blockIdx.x * 4 + wave;
    int bh = base >> 10, i = base & 1023;
    int b = bh / HEADS, h = bh - HEADS * b;
    const float* row = xqkv + ((long)b * Nn + i) * I3 + h * DH;
    float sq, zq, sk, zk, sv, zv;
    get_sz(scal, P_Q, &sq, &zq);
    get_sz(scal, P_K, &sk, &zk);
    get_sz(scal, P_V, &sv, &zv);
    float q = rintf(row[d] / sq + zq);
    float k = rintf(row[768 + d] / sk + zk);
    float v = rintf(row[1536 + d] / sv + zv);
    long o = (long)base * 64 + d;
    qq[o] = (signed char)(int)q;
    kq[o] = (signed char)(int)k;
    vqT[((long)bh * 64 + d) * 1024 + i] = (signed char)(int)v;
    float s1 = q, s2 = k;
    for (int off = 32; off > 0; off >>= 1) {
        s1 += __shfl_down(s1, off);
        s2 += __shfl_down(s2, off);
    }
    if (d == 0) { rowsum_qq[base] = s1; colsum_kq[base] = s2; }
}

// column sums of V (over keys j) from vqT rows — contiguous reads
__global__ __launch_bounds__(256) void k_colsum_vq(const signed char* vqT, float* colsum) {
    __shared__ float red[256];
    int tid = threadIdx.x;
    const signed char* row = vqT + (long)blockIdx.x * 1024;
    float acc = 0.f;
    for (int j = tid; j < Nn; j += 256) acc += (float)row[j];
    red[tid] = acc; __syncthreads();
    for (int s = 128; s > 0; s >>= 1) { if (tid < s) red[tid] += red[tid + s]; __syncthreads(); }
    if (tid == 0) colsum[blockIdx.x] = red[0];
}

// Pass A: 64 q-rows/block. LDS-staged K (256-key superchunks, reg prefetch).
// Phase 1: max/min sweep. Phase 2: sumexp sweep (__expf; se noise ~1e-6 rel, za flips absorbed).
__global__ __launch_bounds__(256) void k_attn_a2(const signed char* qq, const signed char* kq,
                                                 const float* rowsum_qq, const float* colsum_kq,
                                                 unsigned* scal, float* rowmax, float* sumexp) {
    __shared__ __align__(16) signed char Kls[16384];
    __shared__ float redm[256];
    int blk = blockIdx.x;
    int bh = blk >> 4, itile = blk & 15;
    int tid = threadIdx.x;
    int wave = tid >> 6, lane = tid & 63;
    int col16 = lane & 15, quad = lane >> 4;
    int rowbase = itile * 64 + wave * 16;
    const signed char* kbase = kq + (long)bh * Nn * 64;
    const float* csk_base = colsum_kq + bh * Nn;
    v4i afrag = *(const v4i*)(qq + ((long)bh * Nn + rowbase + col16) * 64 + quad * 16);
    float sq, zq, sk, zk;
    get_sz(scal, P_Q, &sq, &zq);
    get_sz(scal, P_K, &sk, &zk);
    float csc = (0.125f * sq) * sk;
    float rsq[4];
#pragma unroll
    for (int r = 0; r < 4; ++r) rsq[r] = rowsum_qq[bh * Nn + rowbase + quad * 4 + r];

    // staging map: issue i covers key_local=(i*4+wave)*16+(tid&15), byte chunk ((tid>>4)&3)*16
    int skey = ((tid & 15)) * 64 + ((tid >> 4) & 3) * 16;   // within 16-key group: row*64+chunk
    int ldsoff = tid * 16;
    v4i rk[4];
#define LOADK(sc)  { _Pragma("unroll") for (int i = 0; i < 4; ++i) \
        rk[i] = *(const v4i*)(kbase + ((long)(sc) * 256 + (i * 4 + wave) * 16) * 64 + skey); }
#define STOREK()   { _Pragma("unroll") for (int i = 0; i < 4; ++i) \
        *(v4i*)(Kls + i * 4096 + ldsoff) = rk[i]; }

    v4i zero = {0, 0, 0, 0};
    float lmax[4] = {-INFINITY, -INFINITY, -INFINITY, -INFINITY};
    float lmin[4] = {INFINITY, INFINITY, INFINITY, INFINITY};
    LOADK(0);
    for (int sc = 0; sc < 4; ++sc) {
        __syncthreads();
        STOREK();
        __syncthreads();
        if (sc < 3) LOADK(sc + 1);
#pragma unroll
        for (int u = 0; u < 16; ++u) {
            v4i bfrag = *(const v4i*)(Kls + u * 1024 + quad * 256 + col16 * 16);
            v4i d = __builtin_amdgcn_mfma_i32_16x16x64_i8(afrag, bfrag, zero, 0, 0, 0);
            float csk = csk_base[sc * 256 + u * 16 + col16] * zq;
#pragma unroll
            for (int r = 0; r < 4; ++r) {
                float dv = ((float)d[r] - csk - rsq[r] * zk) * csc;
                lmax[r] = fmaxf(lmax[r], dv);
                lmin[r] = fminf(lmin[r], dv);
            }
        }
    }
#pragma unroll
    for (int r = 0; r < 4; ++r) {
        for (int off = 1; off < 16; off <<= 1) {
            lmax[r] = fmaxf(lmax[r], __shfl_xor(lmax[r], off));
            lmin[r] = fminf(lmin[r], __shfl_xor(lmin[r], off));
        }
    }
    float se[4] = {0.f, 0.f, 0.f, 0.f};
    LOADK(0);
    for (int sc = 0; sc < 4; ++sc) {
        __syncthreads();
        STOREK();
        __syncthreads();
        if (sc < 3) LOADK(sc + 1);
#pragma unroll
        for (int u = 0; u < 16; ++u) {
            v4i bfrag = *(const v4i*)(Kls + u * 1024 + quad * 256 + col16 * 16);
            v4i d = __builtin_amdgcn_mfma_i32_16x16x64_i8(afrag, bfrag, zero, 0, 0, 0);
            float csk = csk_base[sc * 256 + u * 16 + col16] * zq;
#pragma unroll
            for (int r = 0; r < 4; ++r) {
                float dv = ((float)d[r] - csk - rsq[r] * zk) * csc;
                se[r] += __expf(dv - lmax[r]);
            }
        }
    }
#undef LOADK
#undef STOREK
#pragma unroll
    for (int r = 0; r < 4; ++r)
        for (int off = 1; off < 16; off <<= 1) se[r] += __shfl_xor(se[r], off);
    float amax_c = -INFINITY, amin_c = INFINITY;
    if (col16 == 0) {
#pragma unroll
        for (int r = 0; r < 4; ++r) {
            int row = bh * Nn + rowbase + quad * 4 + r;
            rowmax[row] = lmax[r];
            sumexp[row] = se[r];
            amax_c = fmaxf(amax_c, 1.0f / se[r]);
            amin_c = fminf(amin_c, __expf(lmin[r] - lmax[r]) / se[r]);
        }
    }
    redm[tid] = amax_c; __syncthreads();
    for (int s = 128; s > 0; s >>= 1) { if (tid < s) redm[tid] = fmaxf(redm[tid], redm[tid + s]); __syncthreads(); }
    if (tid == 0) atomicMax(&scal[2 * P_A + 1], encf(redm[0]));
    __syncthreads();
    redm[tid] = amin_c; __syncthreads();
    for (int s = 128; s > 0; s >>= 1) { if (tid < s) redm[tid] = fminf(redm[tid], redm[tid + s]); __syncthreads(); }
    if (tid == 0) atomicMin(&scal[2 * P_A], encf(redm[0]));
}

// Pass B: LDS-staged K+V (256-key superchunks, reg prefetch), quantize a (guarded fast path),
// double-buffered Aq relayout, PV MFMA. Fused P_O minmax.
__global__ __launch_bounds__(256) void k_attn_b2(const signed char* qq, const signed char* kq,
                                                 const signed char* vqT, const float* rowsum_qq,
                                                 const float* colsum_kq, const float* colsum_vq,
                                                 const float* rowmax, const float* sumexp,
                                                 unsigned* scal, float* out_mat) {
    __shared__ __align__(16) signed char Kls[16384];
    __shared__ __align__(16) signed char Vls[16384];
    __shared__ __align__(16) signed char AqB[8192];
    __shared__ float red[256];
    int blk = blockIdx.x;
    int bh = blk >> 4, itile = blk & 15;
    int tid = threadIdx.x;
    int wave = tid >> 6, lane = tid & 63;
    int col16 = lane & 15, quad = lane >> 4;
    int rowbase = itile * 64 + wave * 16;
    int b = bh / HEADS, h = bh - HEADS * b;
    const signed char* kbase = kq + (long)bh * Nn * 64;
    const signed char* vbase = vqT + (long)bh * 64 * 1024;
    const float* csk_base = colsum_kq + bh * Nn;
    v4i afrag = *(const v4i*)(qq + ((long)bh * Nn + rowbase + col16) * 64 + quad * 16);
    float sq, zq, sk, zk, sv, zv, sa, za;
    get_sz(scal, P_Q, &sq, &zq);
    get_sz(scal, P_K, &sk, &zk);
    get_sz(scal, P_V, &sv, &zv);
    get_sz(scal, P_A, &sa, &za);
    float csc = (0.125f * sq) * sk;
    float rsq[4], m[4], se[4], crcp[4];
#pragma unroll
    for (int r = 0; r < 4; ++r) {
        int row = bh * Nn + rowbase + quad * 4 + r;
        rsq[r] = rowsum_qq[row];
        m[r] = rowmax[row];
        se[r] = sumexp[row];
        crcp[r] = 1.0f / (se[r] * sa);
    }

    // staging maps (see pass A for K); V: issue i covers d=i*16+(tid&15), keys (tid>>4)*16
    int skey = ((tid & 15)) * 64 + ((tid >> 4) & 3) * 16;
    int ldsoff = tid * 16;
    v4i rk[4], rv[4];
#define LOADKV(sc) { _Pragma("unroll") for (int i = 0; i < 4; ++i) { \
        rk[i] = *(const v4i*)(kbase + ((long)(sc) * 256 + (i * 4 + wave) * 16) * 64 + skey); \
        rv[i] = *(const v4i*)(vbase + (long)(i * 16 + (tid & 15)) * 1024 + (sc) * 256 + (tid >> 4) * 16); } }
#define STOREKV()  { _Pragma("unroll") for (int i = 0; i < 4; ++i) { \
        *(v4i*)(Kls + i * 4096 + ldsoff) = rk[i]; \
        *(v4i*)(Vls + i * 4096 + ldsoff) = rv[i]; } }

    v4i accPV[4] = {};
    float rs_a[4] = {0.f, 0.f, 0.f, 0.f};
    v4i zero = {0, 0, 0, 0};
    LOADKV(0);
    for (int sc = 0; sc < 4; ++sc) {
        __syncthreads();
        STOREKV();
        __syncthreads();
        if (sc < 3) LOADKV(sc + 1);
#pragma unroll
        for (int ci = 0; ci < 4; ++ci) {
            signed char* myAq = AqB + (ci & 1) * 4096 + wave * 1024;
#pragma unroll
            for (int u = 0; u < 4; ++u) {
                int kt = ci * 4 + u;
                v4i bfrag = *(const v4i*)(Kls + kt * 1024 + quad * 256 + col16 * 16);
                v4i d = __builtin_amdgcn_mfma_i32_16x16x64_i8(afrag, bfrag, zero, 0, 0, 0);
                float csk = csk_base[sc * 256 + kt * 16 + col16] * zq;
#pragma unroll
                for (int r = 0; r < 4; ++r) {
                    float dv = ((float)d[r] - csk - rsq[r] * zk) * csc;
                    float es = dv - m[r];
                    float fastv = fmaf(__expf(es), crcp[r], za);
                    float fr = fastv - floorf(fastv);
                    if (fabsf(fr - 0.5f) < 1.5e-4f) {
                        float av = expf(es) / se[r];
                        fastv = av / sa + za;
                    }
                    float aqv = rintf(fastv);
                    rs_a[r] += aqv;
                    myAq[(quad * 4 + r) * 64 + u * 16 + col16] = (signed char)(int)aqv;
                }
            }
            asm volatile("s_waitcnt lgkmcnt(0)" ::: "memory");
            v4i pa = *(const v4i*)(myAq + col16 * 64 + quad * 16);
#pragma unroll
            for (int g = 0; g < 4; ++g) {
                v4i bv = *(const v4i*)(Vls + g * 4096 + (ci * 4 + quad) * 256 + col16 * 16);
                accPV[g] = __builtin_amdgcn_mfma_i32_16x16x64_i8(pa, bv, accPV[g], 0, 0, 0);
            }
        }
    }
#undef LOADKV
#undef STOREKV
#pragma unroll
    for (int r = 0; r < 4; ++r)
        for (int off = 1; off < 16; off <<= 1) rs_a[r] += __shfl_xor(rs_a[r], off);
    float sav = sa * sv;
    float zz = (za * zv) * 1024.0f;
    float vmn = INFINITY, vmx = -INFINITY;
#pragma unroll
    for (int g = 0; g < 4; ++g) {
        int d = g * 16 + col16;
        float cs = colsum_vq[bh * 64 + d] * za;
#pragma unroll
        for (int r = 0; r < 4; ++r) {
            int i = rowbase + quad * 4 + r;
            float v = ((float)accPV[g][r] - cs - rs_a[r] * zv + zz) * sav;
            out_mat[((long)b * Nn + i) * Dm + h * DH + d] = v;
            vmn = fminf(vmn, v); vmx = fmaxf(vmx, v);
        }
    }
    red[tid] = vmx; __syncthreads();
    for (int s = 128; s > 0; s >>= 1) { if (tid < s) red[tid] = fmaxf(red[tid], red[tid + s]); __syncthreads(); }
    if (tid == 0) atomicMax(&scal[2 * P_O + 1], encf(red[0]));
    __syncthreads();
    red[tid] = vmn; __syncthreads();
    for (int s = 128; s > 0; s >>= 1) { if (tid < s) red[tid] = fminf(red[tid], red[tid + s]); __syncthreads(); }
    if (tid == 0) atomicMin(&scal[2 * P_O], encf(red[0]));
}

// ---------- launch ----------
extern "C" void kernel_launch(void* const* d_in, const int* in_sizes, int n_in,
                              void* d_out, int out_size, void* d_ws, size_t ws_size,
                              hipStream_t stream) {
    const float* x     = (const float*)d_in[0];
    const float* w_qkv = (const float*)d_in[1];
    const float* w_out = (const float*)d_in[2];
    const float* b_out = (const float*)d_in[3];

    char* ws = (char*)d_ws;
    size_t off = 0;
    auto alloc = [&](size_t n) -> char* {
        char* p = ws + off;
        off = (off + n + 255) & ~(size_t)255;
        return p;
    };
    unsigned*    scal        = (unsigned*)alloc(64);
    float*       xqkv        = (float*)alloc((size_t)Mm * I3 * 4);
    float*       out_mat     = (float*)alloc((size_t)Mm * Dm * 4);
    signed char* xq          = (signed char*)alloc((size_t)Mm * Dm);
    signed char* wq          = (signed char*)alloc((size_t)I3 * Dm);
    signed char* w2q         = (signed char*)alloc((size_t)Dm * Dm);
    signed char* oq          = (signed char*)alloc((size_t)Mm * Dm);
    signed char* qq          = (signed char*)alloc((size_t)BHt * Nn * DH);
    signed char* kq          = (signed char*)alloc((size_t)BHt * Nn * DH);
    signed char* vqT         = (signed char*)alloc((size_t)BHt * Nn * DH);
    float*       rowsum_xq   = (float*)alloc((size_t)Mm * 4);
    float*       colsum_w1   = (float*)alloc((size_t)I3 * 4);
    float*       colsum_w2   = (float*)alloc((size_t)Dm * 4);
    float*       rowsum_xqkv = (float*)alloc((size_t)Mm * 4);
    float*       rowsum_qq   = (float*)alloc((size_t)BHt * Nn * 4);
    float*       colsum_kq   = (float*)alloc((size_t)BHt * Nn * 4);
    float*       colsum_vq   = (float*)alloc((size_t)BHt * DH * 4);
    float*       rowmax      = (float*)alloc((size_t)BHt * Nn * 4);
    float*       sumexp      = (float*)alloc((size_t)BHt * Nn * 4);
    float*       oq_rowsum   = (float*)alloc((size_t)Mm * 4);

    k_init<<<16, 256, 0, stream>>>(scal, rowsum_xqkv, Mm);

    k_minmax3<<<448, 256, 0, stream>>>(x, w_qkv, w_out, scal);
    k_quant3<<<7168, 256, 0, stream>>>(x, w_qkv, w_out, scal, xq, wq, w2q,
                                       rowsum_xq, colsum_w1, colsum_w2);

    {   // GEMM1 + fused xqkv row sums and Q/K/V minmax
        dim3 g(I3 / 128, Mm / 128);
        k_gemm_mfma<<<g, 256, 0, stream>>>(xq, wq, colsum_w1, rowsum_xq, nullptr, xqkv,
                                           Dm, I3, scal, P_X, P_W1, 768.0f,
                                           1, rowsum_xqkv, scal);
    }

    k_quant_qkv<<<BHt * Nn / 4, 256, 0, stream>>>(xqkv, scal, qq, kq, vqT, rowsum_qq, colsum_kq);
    k_colsum_vq<<<BHt * DH, 256, 0, stream>>>(vqT, colsum_vq);

    k_attn_a2<<<BHt * 16, 256, 0, stream>>>(qq, kq, rowsum_qq, colsum_kq, scal, rowmax, sumexp);
    k_attn_b2<<<BHt * 16, 256, 0, stream>>>(qq, kq, vqT, rowsum_qq, colsum_kq, colsum_vq,
                                            rowmax, sumexp, scal, out_mat);

    k_quant_rows<<<Mm, 256, 0, stream>>>(out_mat, scal, P_O, oq, oq_rowsum);

    {   // GEMM2 (+bias)
        dim3 g(Dm / 128, Mm / 128);
        k_gemm_mfma<<<g, 256, 0, stream>>>(oq, w2q, colsum_w2, rowsum_xqkv, b_out, (float*)d_out,
                                           Dm, Dm, scal, P_O, P_W2, 2304.0f,
                                           0, nullptr, nullptr);
    }
}